// Round 2
// baseline (634.249 us; speedup 1.0000x reference)
//
#include <hip/hip_runtime.h>

typedef __attribute__((ext_vector_type(8))) short short8;
typedef __attribute__((ext_vector_type(4))) float floatx4;

#define B_  64
#define N_  4096
#define DIN 192
#define S_  11
#define E_  128

__device__ inline unsigned short f2bf(float f) {
    union { float f; unsigned u; } v; v.f = f;
    unsigned r = v.u + 0x7FFF + ((v.u >> 16) & 1);
    return (unsigned short)(r >> 16);
}
__device__ inline floatx4 fzero4() { floatx4 v; v[0]=v[1]=v[2]=v[3]=0.f; return v; }

// ---------------------------------------------------------------- K0: weight prep
// Wf = K/V weights (ln_in_g folded), stored in MFMA B-fragment order:
//   Wf[((nt*6 + kk)*64 + g*16 + c)*8 + j] = W[nt*16+c][kk*32 + g*8 + j] * ln_in_g[...]
// bias_kv[o] = sum_j ln_in_b[j]*W[o][j]
// Wq_s[e][j] = Wq[e][j] * ln_s_g[j] * scale, bias_q[e] = scale * sum_j ln_s_b[j]*Wq[e][j]
__global__ void k0_prep(const float* __restrict__ Wk, const float* __restrict__ Wv,
                        const float* __restrict__ ln_in_g, const float* __restrict__ ln_in_b,
                        const float* __restrict__ Wq, const float* __restrict__ ln_s_g,
                        const float* __restrict__ ln_s_b,
                        unsigned short* __restrict__ Wf, float* __restrict__ bias_kv,
                        float* __restrict__ Wq_s, float* __restrict__ bias_q) {
    int o = blockIdx.x, t = threadIdx.x;
    if (o < 256) {
        const float* src = (o < 128) ? (Wk + (size_t)o * DIN) : (Wv + (size_t)(o - 128) * DIN);
        int nt = o >> 4, cc = o & 15;
        float bs = 0.f;
        for (int j = t; j < DIN; j += 64) {
            float w = src[j];
            int kk = j >> 5, gg = (j >> 3) & 3, jj = j & 7;
            Wf[(size_t)(((nt * 6 + kk) << 6) + gg * 16 + cc) * 8 + jj] = f2bf(w * ln_in_g[j]);
            bs += w * ln_in_b[j];
        }
        #pragma unroll
        for (int off = 32; off > 0; off >>= 1) bs += __shfl_down(bs, off);
        if (t == 0) bias_kv[o] = bs;
    } else {
        int e = o - 256;
        const float sc = 0.08838834764831845f;  // 1/sqrt(128)
        float bs = 0.f;
        for (int j = t; j < E_; j += 64) {
            float w = Wq[(size_t)e * E_ + j];
            Wq_s[(size_t)e * E_ + j] = w * ln_s_g[j] * sc;
            bs += w * ln_s_b[j];
        }
        #pragma unroll
        for (int off = 32; off > 0; off >>= 1) bs += __shfl_down(bs, off);
        if (t == 0) bias_q[e] = bs * sc;
    }
}

// ---------------------------------------------------------------- K1: LN + K/V projection (MFMA)
// Register LN (lane owns its A-fragment's row slice), weights streamed from
// global in fragment order (L2-resident). LDS only for the V transpose.
#define VP 72
__global__ __launch_bounds__(256)
void k1_lnproj(const float* __restrict__ inp, const unsigned short* __restrict__ Wf,
               const float* __restrict__ bias_kv,
               unsigned short* __restrict__ k1o, unsigned short* __restrict__ v1T) {
    __shared__ unsigned short Vl[128][VP];   // 18432 B
    int t = threadIdx.x, lane = t & 63, wid = t >> 6;
    long rowbase = (long)blockIdx.x * 64;
    int bb = (int)(rowbase >> 12);
    int nbase = (int)(rowbase & 4095);
    int c = lane & 15, g = lane >> 4;

    // ---- load this lane's 48 input floats (row = rowbase + wid*16 + c)
    long row = rowbase + wid * 16 + c;
    const float* rp = inp + row * DIN;
    floatx4 x[12];
    #pragma unroll
    for (int kk = 0; kk < 6; ++kk) {
        x[2 * kk]     = *(const floatx4*)(rp + kk * 32 + g * 8);
        x[2 * kk + 1] = *(const floatx4*)(rp + kk * 32 + g * 8 + 4);
    }
    // ---- LN stats across the 4 lanes sharing this row (lane ^ 16, ^ 32)
    float s1 = 0.f, s2 = 0.f;
    #pragma unroll
    for (int j = 0; j < 12; ++j) {
        #pragma unroll
        for (int e = 0; e < 4; ++e) { s1 += x[j][e]; s2 += x[j][e] * x[j][e]; }
    }
    s1 += __shfl_xor(s1, 16); s1 += __shfl_xor(s1, 32);
    s2 += __shfl_xor(s2, 16); s2 += __shfl_xor(s2, 32);
    float mean = s1 * (1.f / 192.f);
    float var  = s2 * (1.f / 192.f) - mean * mean;
    float rsd  = rsqrtf(var + 1e-5f);
    // ---- pack A fragments
    short8 af[6];
    #pragma unroll
    for (int kk = 0; kk < 6; ++kk) {
        short8 f;
        #pragma unroll
        for (int e = 0; e < 4; ++e) {
            f[e]     = (short)f2bf((x[2 * kk][e]     - mean) * rsd);
            f[4 + e] = (short)f2bf((x[2 * kk + 1][e] - mean) * rsd);
        }
        af[kk] = f;
    }
    // ---- MFMA: B fragments streamed from global (contiguous 1 KiB per wave read)
    floatx4 acc[16];
    #pragma unroll
    for (int i = 0; i < 16; ++i) acc[i] = fzero4();
    #pragma unroll
    for (int kk = 0; kk < 6; ++kk) {
        #pragma unroll
        for (int nt = 0; nt < 16; ++nt) {
            short8 bf = *(const short8*)(Wf + (size_t)(((nt * 6 + kk) << 6) + lane) * 8);
            acc[nt] = __builtin_amdgcn_mfma_f32_16x16x32_bf16(af[kk], bf, acc[nt], 0, 0, 0);
        }
    }
    // ---- K outputs: tiles 0..7, row-major bf16 [B*N][128]
    #pragma unroll
    for (int nt = 0; nt < 8; ++nt) {
        int col = nt * 16 + c;
        float bia = bias_kv[col];
        #pragma unroll
        for (int r = 0; r < 4; ++r) {
            long orow = rowbase + wid * 16 + g * 4 + r;
            k1o[orow * 128 + col] = f2bf(acc[nt][r] + bia);
        }
    }
    // ---- V outputs -> LDS transpose
    #pragma unroll
    for (int nt = 8; nt < 16; ++nt) {
        int d = (nt - 8) * 16 + c;
        float bia = bias_kv[128 + d];
        #pragma unroll
        for (int r = 0; r < 4; ++r)
            Vl[d][wid * 16 + g * 4 + r] = f2bf(acc[nt][r] + bia);
    }
    __syncthreads();
    // ---- v1T[b][d][n]: thread t -> d = t>>1, half = t&1 (32 n each)
    {
        int dd = t >> 1, hf = t & 1;
        const short8* srcv = (const short8*)(&Vl[dd][hf * 32]);
        short8 y0 = srcv[0], y1 = srcv[1], y2 = srcv[2], y3 = srcv[3];
        short8* dstv = (short8*)(v1T + (((size_t)bb * 128 + dd) << 12) + nbase + hf * 32);
        dstv[0] = y0; dstv[1] = y1; dstv[2] = y2; dstv[3] = y3;
    }
}

// ---------------------------------------------------------------- K2: slot init (LN + optional MHA + MLP)
__global__ __launch_bounds__(256)
void k2_init(const float* __restrict__ islots, const int* __restrict__ ip,
             const float* __restrict__ ln_s_g, const float* __restrict__ ln_s_b,
             const float* __restrict__ in_w, const float* __restrict__ in_b,
             const float* __restrict__ out_w, const float* __restrict__ out_b,
             const float* __restrict__ w1, const float* __restrict__ b1,
             const float* __restrict__ w2, const float* __restrict__ b2,
             float* __restrict__ slotsA) {
    __shared__ float sl[11][128];
    __shared__ float qkv[11][384];
    __shared__ float att[4][11][12];
    __shared__ float oh[11][128];
    __shared__ float s2l[11][128];
    __shared__ float s3[11][128];
    __shared__ float h1[11][256];
    int t = threadIdx.x, lane = t & 63, wid = t >> 6;
    int bb = blockIdx.x;

    for (int s = wid; s < 11; s += 4) {
        const float* row = islots + ((size_t)bb * 11 + s) * 128;
        float x0 = row[lane], x1 = row[lane + 64];
        float s1 = x0 + x1, sq = x0 * x0 + x1 * x1;
        #pragma unroll
        for (int off = 32; off > 0; off >>= 1) { s1 += __shfl_xor(s1, off); sq += __shfl_xor(sq, off); }
        float mean = s1 * (1.f / 128.f), var = sq * (1.f / 128.f) - mean * mean;
        float rs = rsqrtf(var + 1e-5f);
        sl[s][lane]      = (x0 - mean) * rs * ln_s_g[lane]      + ln_s_b[lane];
        sl[s][lane + 64] = (x1 - mean) * rs * ln_s_g[lane + 64] + ln_s_b[lane + 64];
    }
    __syncthreads();
    int ival = *ip;
    if (ival != 1) {
        for (int o = t; o < 11 * 384; o += 256) {
            int s = o / 384, e = o % 384;
            const floatx4* w = (const floatx4*)(in_w + (size_t)e * 128);
            const floatx4* x = (const floatx4*)sl[s];
            float a = 0.f;
            for (int j = 0; j < 32; ++j) {
                floatx4 wv = w[j], xv = x[j];
                a += wv[0]*xv[0] + wv[1]*xv[1] + wv[2]*xv[2] + wv[3]*xv[3];
            }
            qkv[s][e] = a + in_b[e];
        }
        __syncthreads();
        for (int o = t; o < 4 * 11 * 11; o += 256) {
            int h = o / 121, ij = o % 121, i = ij / 11, j = ij % 11;
            const float* qr = &qkv[i][h * 32];
            const float* kr = &qkv[j][128 + h * 32];
            float a = 0.f;
            #pragma unroll
            for (int d = 0; d < 32; ++d) a += qr[d] * kr[d];
            att[h][i][j] = a * 0.17677669529663687f;
        }
        __syncthreads();
        if (t < 44) {
            int h = t / 11, i = t % 11;
            float mx = -1e30f;
            #pragma unroll
            for (int j = 0; j < 11; ++j) mx = fmaxf(mx, att[h][i][j]);
            float sum = 0.f, e_[11];
            #pragma unroll
            for (int j = 0; j < 11; ++j) { e_[j] = __expf(att[h][i][j] - mx); sum += e_[j]; }
            float inv = 1.f / sum;
            #pragma unroll
            for (int j = 0; j < 11; ++j) att[h][i][j] = e_[j] * inv;
        }
        __syncthreads();
        for (int o = t; o < 11 * 128; o += 256) {
            int s = o >> 7, e = o & 127, h = e >> 5;
            float a = 0.f;
            #pragma unroll
            for (int j = 0; j < 11; ++j) a += att[h][s][j] * qkv[j][256 + e];
            oh[s][e] = a;
        }
        __syncthreads();
        for (int o = t; o < 11 * 128; o += 256) {
            int s = o >> 7, e = o & 127;
            const floatx4* w = (const floatx4*)(out_w + (size_t)e * 128);
            const floatx4* x = (const floatx4*)oh[s];
            float a = 0.f;
            for (int j = 0; j < 32; ++j) {
                floatx4 wv = w[j], xv = x[j];
                a += wv[0]*xv[0] + wv[1]*xv[1] + wv[2]*xv[2] + wv[3]*xv[3];
            }
            s2l[s][e] = sl[s][e] + a + out_b[e];
        }
        __syncthreads();
        for (int s = wid; s < 11; s += 4) {
            float x0 = s2l[s][lane], x1 = s2l[s][lane + 64];
            float s1 = x0 + x1, sq = x0 * x0 + x1 * x1;
            #pragma unroll
            for (int off = 32; off > 0; off >>= 1) { s1 += __shfl_xor(s1, off); sq += __shfl_xor(sq, off); }
            float mean = s1 * (1.f / 128.f), var = sq * (1.f / 128.f) - mean * mean;
            float rs = rsqrtf(var + 1e-5f);
            s3[s][lane]      = (x0 - mean) * rs * ln_s_g[lane]      + ln_s_b[lane];
            s3[s][lane + 64] = (x1 - mean) * rs * ln_s_g[lane + 64] + ln_s_b[lane + 64];
        }
        __syncthreads();
        for (int o = t; o < 11 * 256; o += 256) {
            int s = o >> 8, k = o & 255;
            const floatx4* w = (const floatx4*)(w1 + (size_t)k * 128);
            const floatx4* x = (const floatx4*)s3[s];
            float a = 0.f;
            for (int j = 0; j < 32; ++j) {
                floatx4 wv = w[j], xv = x[j];
                a += wv[0]*xv[0] + wv[1]*xv[1] + wv[2]*xv[2] + wv[3]*xv[3];
            }
            a += b1[k];
            h1[s][k] = a > 0.f ? a : 0.f;
        }
        __syncthreads();
        for (int o = t; o < 11 * 128; o += 256) {
            int s = o >> 7, e = o & 127;
            const floatx4* w = (const floatx4*)(w2 + (size_t)e * 256);
            const floatx4* x = (const floatx4*)h1[s];
            float a = 0.f;
            for (int j = 0; j < 64; ++j) {
                floatx4 wv = w[j], xv = x[j];
                a += wv[0]*xv[0] + wv[1]*xv[1] + wv[2]*xv[2] + wv[3]*xv[3];
            }
            slotsA[((size_t)bb * 11 + s) * 128 + e] = s3[s][e] + a + b2[e];
        }
    } else {
        for (int o = t; o < 11 * 128; o += 256) {
            int s = o >> 7, e = o & 127;
            slotsA[((size_t)bb * 11 + s) * 128 + e] = sl[s][e];
        }
    }
}

// ---------------------------------------------------------------- K3: q = LN(slots) @ Wq' + bias_q
__global__ __launch_bounds__(128)
void k3_q(const float* __restrict__ slots, const float* __restrict__ Wq_s,
          const float* __restrict__ bias_q, float* __restrict__ qbuf) {
    __shared__ float sn[128];
    __shared__ float red[4];
    int t = threadIdx.x;
    int bs = blockIdx.x;
    float x = slots[(size_t)bs * 128 + t];
    float s1 = x, s2 = x * x;
    #pragma unroll
    for (int off = 32; off > 0; off >>= 1) { s1 += __shfl_xor(s1, off); s2 += __shfl_xor(s2, off); }
    if ((t & 63) == 0) { red[(t >> 6) * 2] = s1; red[(t >> 6) * 2 + 1] = s2; }
    __syncthreads();
    float tot1 = red[0] + red[2], tot2 = red[1] + red[3];
    float mean = tot1 * (1.f / 128.f), var = tot2 * (1.f / 128.f) - mean * mean;
    float rs = rsqrtf(var + 1e-5f);
    sn[t] = (x - mean) * rs;
    __syncthreads();
    const floatx4* w = (const floatx4*)(Wq_s + (size_t)t * 128);
    const floatx4* sp = (const floatx4*)sn;
    float a = 0.f;
    for (int j = 0; j < 32; ++j) {
        floatx4 wv = w[j], sv = sp[j];
        a += wv[0]*sv[0] + wv[1]*sv[1] + wv[2]*sv[2] + wv[3]*sv[3];
    }
    qbuf[(size_t)bs * 128 + t] = a + bias_q[t];
}

// ---------------------------------------------------------------- K4: slot attention main
#define LGP 17
#define PPAD 72
struct K4Arena {
    union {
        float Lg[64][LGP];   // 4352 B (logits, per-wave)
        float Ul[16][132];   // 8448 B (update partials, per-wave; reused after Lg dead)
    };
    unsigned short Pl[16][PPAD];  // 2304 B
};
__global__ __launch_bounds__(256)
void k4_attn(const unsigned short* __restrict__ k1, const unsigned short* __restrict__ v1T,
             const float* __restrict__ qbuf, float* __restrict__ Upart, float* __restrict__ Spart) {
    __shared__ K4Arena ar[4];   // 43008 B
    int t = threadIdx.x, lane = t & 63, wid = t >> 6;
    int bb = blockIdx.x >> 4;
    int part = blockIdx.x & 15;
    int n0 = part * 256 + wid * 64;
    int c = lane & 15, g = lane >> 4;
    K4Arena& A = ar[wid];

    short8 bq[4];
    #pragma unroll
    for (int kk = 0; kk < 4; ++kk) {
        short8 f;
        if (c < 11) {
            const floatx4* qp = (const floatx4*)(qbuf + ((size_t)bb * 11 + c) * 128 + kk * 32 + g * 8);
            floatx4 q0 = qp[0], q1 = qp[1];
            #pragma unroll
            for (int e = 0; e < 4; ++e) { f[e] = (short)f2bf(q0[e]); f[4 + e] = (short)f2bf(q1[e]); }
        } else {
            #pragma unroll
            for (int e = 0; e < 8; ++e) f[e] = 0;
        }
        bq[kk] = f;
    }

    floatx4 lac[4];
    #pragma unroll
    for (int t4 = 0; t4 < 4; ++t4) {
        lac[t4] = fzero4();
        #pragma unroll
        for (int kk = 0; kk < 4; ++kk) {
            const short8* ap = (const short8*)(k1 + ((size_t)bb * 4096 + n0 + t4 * 16 + c) * 128 + kk * 32 + g * 8);
            lac[t4] = __builtin_amdgcn_mfma_f32_16x16x32_bf16(*ap, bq[kk], lac[t4], 0, 0, 0);
        }
    }
    #pragma unroll
    for (int t4 = 0; t4 < 4; ++t4)
        #pragma unroll
        for (int r = 0; r < 4; ++r)
            A.Lg[t4 * 16 + g * 4 + r][c] = lac[t4][r];

    // per-lane softmax over 11 slots (row = lane), p = softmax + eps
    float p[11];
    {
        float mx = -1e30f;
        #pragma unroll
        for (int s = 0; s < 11; ++s) { p[s] = A.Lg[lane][s]; mx = fmaxf(mx, p[s]); }
        float sum = 0.f;
        #pragma unroll
        for (int s = 0; s < 11; ++s) { p[s] = __expf(p[s] - mx); sum += p[s]; }
        float inv = 1.f / sum;
        #pragma unroll
        for (int s = 0; s < 11; ++s) p[s] = p[s] * inv + 1e-8f;
    }
    #pragma unroll
    for (int s = 0; s < 11; ++s) A.Pl[s][lane] = f2bf(p[s]);

    floatx4 uac[8];
    floatx4 sac = fzero4();
    #pragma unroll
    for (int dt = 0; dt < 8; ++dt) uac[dt] = fzero4();
    short8 ones;
    #pragma unroll
    for (int e = 0; e < 8; ++e) ones[e] = (short)0x3F80;
    #pragma unroll
    for (int kk = 0; kk < 2; ++kk) {
        short8 ap = *(const short8*)(&A.Pl[c][kk * 32 + g * 8]);
        #pragma unroll
        for (int dt = 0; dt < 8; ++dt) {
            const short8* vp = (const short8*)(v1T + ((size_t)bb * 128 + dt * 16 + c) * 4096 + n0 + kk * 32 + g * 8);
            uac[dt] = __builtin_amdgcn_mfma_f32_16x16x32_bf16(ap, *vp, uac[dt], 0, 0, 0);
        }
        sac = __builtin_amdgcn_mfma_f32_16x16x32_bf16(ap, ones, sac, 0, 0, 0);
    }
    #pragma unroll
    for (int dt = 0; dt < 8; ++dt)
        #pragma unroll
        for (int r = 0; r < 4; ++r)
            A.Ul[g * 4 + r][dt * 16 + c] = uac[dt][r];
    if (c == 0) {
        #pragma unroll
        for (int r = 0; r < 4; ++r) A.Ul[g * 4 + r][128] = sac[r];
    }
    __syncthreads();
    for (int idx = t; idx < 11 * 129; idx += 256) {
        int s = idx / 129, cc = idx % 129;
        float v = ar[0].Ul[s][cc] + ar[1].Ul[s][cc] + ar[2].Ul[s][cc] + ar[3].Ul[s][cc];
        if (cc < 128) Upart[(((size_t)bb * 16 + part) * 11 + s) * 128 + cc] = v;
        else          Spart[((size_t)bb * 16 + part) * 11 + s] = v;
    }
}

// ---------------------------------------------------------------- K5: reduce partials + GRU + LN + MLP
__global__ __launch_bounds__(128)
void k5_gru(const float* __restrict__ Upart, const float* __restrict__ Spart,
            const float* __restrict__ slots_prev,
            const float* __restrict__ wih, const float* __restrict__ whh,
            const float* __restrict__ bih, const float* __restrict__ bhh,
            const float* __restrict__ ln_m_g, const float* __restrict__ ln_m_b,
            const float* __restrict__ w1, const float* __restrict__ b1,
            const float* __restrict__ w2, const float* __restrict__ b2,
            float* __restrict__ out) {
    __shared__ float upd[128];
    __shared__ float sp[128];
    __shared__ float mrow[128];
    __shared__ float hrow[256];
    __shared__ float red[4];
    int t = threadIdx.x;
    int bb = blockIdx.x / 11, s = blockIdx.x % 11;
    float ua = 0.f, sa = 0.f;
    #pragma unroll
    for (int pI = 0; pI < 16; ++pI) {
        ua += Upart[(((size_t)bb * 16 + pI) * 11 + s) * 128 + t];
        sa += Spart[((size_t)bb * 16 + pI) * 11 + s];
    }
    float u = ua / sa;
    upd[t] = u;
    float spv = slots_prev[((size_t)bb * 11 + s) * 128 + t];
    sp[t] = spv;
    __syncthreads();
    float gi[3], gh[3];
    #pragma unroll
    for (int kI = 0; kI < 3; ++kI) {
        int e = t + kI * 128;
        const floatx4* wi = (const floatx4*)(wih + (size_t)e * 128);
        const floatx4* wh = (const floatx4*)(whh + (size_t)e * 128);
        const floatx4* up = (const floatx4*)upd;
        const floatx4* spp = (const floatx4*)sp;
        float a1 = 0.f, a2 = 0.f;
        for (int j = 0; j < 32; ++j) {
            floatx4 wv = wi[j], uv = up[j];
            a1 += wv[0]*uv[0] + wv[1]*uv[1] + wv[2]*uv[2] + wv[3]*uv[3];
            floatx4 w2v = wh[j], sv = spp[j];
            a2 += w2v[0]*sv[0] + w2v[1]*sv[1] + w2v[2]*sv[2] + w2v[3]*sv[3];
        }
        gi[kI] = a1 + bih[e];
        gh[kI] = a2 + bhh[e];
    }
    float r = 1.f / (1.f + __expf(-(gi[0] + gh[0])));
    float z = 1.f / (1.f + __expf(-(gi[1] + gh[1])));
    float nn = tanhf(gi[2] + r * gh[2]);
    float ns = (1.f - z) * nn + z * spv;
    float s1 = ns, s2 = ns * ns;
    #pragma unroll
    for (int off = 32; off > 0; off >>= 1) { s1 += __shfl_xor(s1, off); s2 += __shfl_xor(s2, off); }
    if ((t & 63) == 0) { red[(t >> 6) * 2] = s1; red[(t >> 6) * 2 + 1] = s2; }
    __syncthreads();
    float tot1 = red[0] + red[2], tot2 = red[1] + red[3];
    float mean = tot1 * (1.f / 128.f), var = tot2 * (1.f / 128.f) - mean * mean;
    float rs = rsqrtf(var + 1e-5f);
    mrow[t] = (ns - mean) * rs * ln_m_g[t] + ln_m_b[t];
    __syncthreads();
    #pragma unroll
    for (int kI = 0; kI < 2; ++kI) {
        int k = t + kI * 128;
        const floatx4* wv = (const floatx4*)(w1 + (size_t)k * 128);
        const floatx4* mp = (const floatx4*)mrow;
        float a = 0.f;
        for (int j = 0; j < 32; ++j) {
            floatx4 w_ = wv[j], m_ = mp[j];
            a += w_[0]*m_[0] + w_[1]*m_[1] + w_[2]*m_[2] + w_[3]*m_[3];
        }
        a += b1[k];
        hrow[k] = a > 0.f ? a : 0.f;
    }
    __syncthreads();
    {
        const floatx4* wv = (const floatx4*)(w2 + (size_t)t * 256);
        const floatx4* hp = (const floatx4*)hrow;
        float a = 0.f;
        for (int j = 0; j < 64; ++j) {
            floatx4 w_ = wv[j], h_ = hp[j];
            a += w_[0]*h_[0] + w_[1]*h_[1] + w_[2]*h_[2] + w_[3]*h_[3];
        }
        out[((size_t)bb * 11 + s) * 128 + t] = ns + a + b2[t];
    }
}

// ---------------------------------------------------------------- host
extern "C" void kernel_launch(void* const* d_in, const int* in_sizes, int n_in,
                              void* d_out, int out_size, void* d_ws, size_t ws_size,
                              hipStream_t stream) {
    const float* inputs   = (const float*)d_in[0];
    const float* islots   = (const float*)d_in[1];
    const int*   ip       = (const int*)d_in[2];
    const float* ln_in_g  = (const float*)d_in[3];
    const float* ln_in_b  = (const float*)d_in[4];
    const float* ln_s_g   = (const float*)d_in[5];
    const float* ln_s_b   = (const float*)d_in[6];
    const float* ln_m_g   = (const float*)d_in[7];
    const float* ln_m_b   = (const float*)d_in[8];
    const float* mha_in_w = (const float*)d_in[9];
    const float* mha_in_b = (const float*)d_in[10];
    const float* mha_out_w= (const float*)d_in[11];
    const float* mha_out_b= (const float*)d_in[12];
    const float* attn_w1  = (const float*)d_in[13];
    const float* attn_b1  = (const float*)d_in[14];
    const float* attn_w2  = (const float*)d_in[15];
    const float* attn_b2  = (const float*)d_in[16];
    const float* Wq       = (const float*)d_in[17];
    const float* Wk       = (const float*)d_in[18];
    const float* Wv       = (const float*)d_in[19];
    const float* gru_wih  = (const float*)d_in[20];
    const float* gru_whh  = (const float*)d_in[21];
    const float* gru_bih  = (const float*)d_in[22];
    const float* gru_bhh  = (const float*)d_in[23];
    const float* mlp_w1   = (const float*)d_in[24];
    const float* mlp_b1   = (const float*)d_in[25];
    const float* mlp_w2   = (const float*)d_in[26];
    const float* mlp_b2   = (const float*)d_in[27];
    float* out = (float*)d_out;

    char* ws = (char*)d_ws;
    size_t off = 0;
    auto alloc = [&](size_t bytes) -> void* {
        void* p = ws + off;
        off += (bytes + 255) & ~(size_t)255;
        return p;
    };
    unsigned short* Wf    = (unsigned short*)alloc((size_t)256 * 192 * 2);
    float* bias_kv        = (float*)alloc(256 * 4);
    float* Wq_s           = (float*)alloc(128 * 128 * 4);
    float* bias_q         = (float*)alloc(128 * 4);
    unsigned short* k1    = (unsigned short*)alloc((size_t)64 * 4096 * 128 * 2);
    unsigned short* v1T   = (unsigned short*)alloc((size_t)64 * 128 * 4096 * 2);
    float* slotsA         = (float*)alloc((size_t)64 * 11 * 128 * 4);
    float* slotsB         = (float*)alloc((size_t)64 * 11 * 128 * 4);
    float* qbuf           = (float*)alloc((size_t)64 * 11 * 128 * 4);
    float* Upart          = (float*)alloc((size_t)64 * 16 * 11 * 128 * 4);
    float* Spart          = (float*)alloc((size_t)64 * 16 * 11 * 4);
    (void)ws_size; (void)in_sizes; (void)n_in; (void)out_size;

    k0_prep<<<384, 64, 0, stream>>>(Wk, Wv, ln_in_g, ln_in_b, Wq, ln_s_g, ln_s_b,
                                    Wf, bias_kv, Wq_s, bias_q);
    k1_lnproj<<<4096, 256, 0, stream>>>(inputs, Wf, bias_kv, k1, v1T);
    k2_init<<<64, 256, 0, stream>>>(islots, ip, ln_s_g, ln_s_b, mha_in_w, mha_in_b,
                                    mha_out_w, mha_out_b, attn_w1, attn_b1, attn_w2, attn_b2,
                                    slotsA);
    const float* sprev = slotsA;
    for (int it = 0; it < 2; ++it) {
        k3_q<<<704, 128, 0, stream>>>(sprev, Wq_s, bias_q, qbuf);
        k4_attn<<<1024, 256, 0, stream>>>(k1, v1T, qbuf, Upart, Spart);
        float* dst = (it == 1) ? out : slotsB;
        k5_gru<<<704, 128, 0, stream>>>(Upart, Spart, sprev, gru_wih, gru_whh, gru_bih, gru_bhh,
                                        ln_m_g, ln_m_b, mlp_w1, mlp_b1, mlp_w2, mlp_b2, dst);
        sprev = dst;
    }
}

// Round 3
// 615.837 us; speedup vs baseline: 1.0299x; 1.0299x over previous
//
#include <hip/hip_runtime.h>

typedef __attribute__((ext_vector_type(8))) short short8;
typedef __attribute__((ext_vector_type(4))) float floatx4;

#define B_  64
#define N_  4096
#define DIN 192
#define S_  11
#define E_  128

__device__ inline unsigned short f2bf(float f) {
    union { float f; unsigned u; } v; v.f = f;
    unsigned r = v.u + 0x7FFF + ((v.u >> 16) & 1);
    return (unsigned short)(r >> 16);
}
__device__ inline floatx4 fzero4() { floatx4 v; v[0]=v[1]=v[2]=v[3]=0.f; return v; }
__device__ inline void store_bf4(unsigned short* dst, floatx4 v) {
    union { unsigned short u[4]; unsigned long long q; } o;
    o.u[0] = f2bf(v[0]); o.u[1] = f2bf(v[1]); o.u[2] = f2bf(v[2]); o.u[3] = f2bf(v[3]);
    *(unsigned long long*)dst = o.q;
}

// ---------------------------------------------------------------- K0: weight prep
// Wf fragment order: Wf[((nt*6+kk)*64 + g*16 + c)*8 + j] = W[nt*16+c][kk*32+g*8+j] * ln_in_g
__global__ void k0_prep(const float* __restrict__ Wk, const float* __restrict__ Wv,
                        const float* __restrict__ ln_in_g, const float* __restrict__ ln_in_b,
                        const float* __restrict__ Wq, const float* __restrict__ ln_s_g,
                        const float* __restrict__ ln_s_b,
                        unsigned short* __restrict__ Wf, float* __restrict__ bias_kv,
                        float* __restrict__ Wq_s, float* __restrict__ bias_q) {
    int o = blockIdx.x, t = threadIdx.x;
    if (o < 256) {
        const float* src = (o < 128) ? (Wk + (size_t)o * DIN) : (Wv + (size_t)(o - 128) * DIN);
        int nt = o >> 4, cc = o & 15;
        float bs = 0.f;
        for (int j = t; j < DIN; j += 64) {
            float w = src[j];
            int kk = j >> 5, gg = (j >> 3) & 3, jj = j & 7;
            Wf[(size_t)(((nt * 6 + kk) << 6) + gg * 16 + cc) * 8 + jj] = f2bf(w * ln_in_g[j]);
            bs += w * ln_in_b[j];
        }
        #pragma unroll
        for (int off = 32; off > 0; off >>= 1) bs += __shfl_down(bs, off);
        if (t == 0) bias_kv[o] = bs;
    } else {
        int e = o - 256;
        const float sc = 0.08838834764831845f;  // 1/sqrt(128)
        float bs = 0.f;
        for (int j = t; j < E_; j += 64) {
            float w = Wq[(size_t)e * E_ + j];
            Wq_s[(size_t)e * E_ + j] = w * ln_s_g[j] * sc;
            bs += w * ln_s_b[j];
        }
        #pragma unroll
        for (int off = 32; off > 0; off >>= 1) bs += __shfl_down(bs, off);
        if (t == 0) bias_q[e] = bs * sc;
    }
}

// ---------------------------------------------------------------- K1: LN + K/V projection
// 8 waves, each owns 2 output tiles (weights in regs). A staged in LDS fragment-order.
// K tiles: mfma(wf, af) -> cols in regs -> packed row-major stores.
// V tiles: mfma(af, wf) -> rows(n) in regs -> packed d-major stores (no LDS transpose).
__global__ __launch_bounds__(512, 2)
void k1_lnproj(const float* __restrict__ inp, const unsigned short* __restrict__ Wf,
               const float* __restrict__ bias_kv,
               unsigned short* __restrict__ k1o, unsigned short* __restrict__ v1T) {
    __shared__ short8 Al[8 * 6 * 64];   // 48 KB: [rg][kk][lane]
    int t = threadIdx.x, lane = t & 63, wid = t >> 6;
    long rowbase = (long)blockIdx.x * 128;
    int bb = (int)(rowbase >> 12);
    int nbase = (int)(rowbase & 4095);
    int c = lane & 15, g = lane >> 4;
    int nt0 = wid * 2;

    // ---- W fragments -> registers (12 x 16B, once per block)
    short8 wf[2][6];
    #pragma unroll
    for (int p = 0; p < 2; ++p)
        #pragma unroll
        for (int kk = 0; kk < 6; ++kk)
            wf[p][kk] = *(const short8*)(Wf + (size_t)(((nt0 + p) * 6 + kk) * 64 + lane) * 8);

    // ---- load this lane's 48 input floats (row = rowbase + wid*16 + c)
    long row = rowbase + wid * 16 + c;
    const float* rp = inp + row * DIN;
    floatx4 x[12];
    #pragma unroll
    for (int kk = 0; kk < 6; ++kk) {
        x[2 * kk]     = *(const floatx4*)(rp + kk * 32 + g * 8);
        x[2 * kk + 1] = *(const floatx4*)(rp + kk * 32 + g * 8 + 4);
    }
    // ---- LN stats across the 4 lanes sharing this row
    float s1 = 0.f, s2 = 0.f;
    #pragma unroll
    for (int j = 0; j < 12; ++j)
        #pragma unroll
        for (int e = 0; e < 4; ++e) { s1 += x[j][e]; s2 += x[j][e] * x[j][e]; }
    s1 += __shfl_xor(s1, 16); s1 += __shfl_xor(s1, 32);
    s2 += __shfl_xor(s2, 16); s2 += __shfl_xor(s2, 32);
    float mean = s1 * (1.f / 192.f);
    float var  = s2 * (1.f / 192.f) - mean * mean;
    float rsd  = rsqrtf(var + 1e-5f);
    // ---- pack A fragments -> LDS
    #pragma unroll
    for (int kk = 0; kk < 6; ++kk) {
        short8 f;
        #pragma unroll
        for (int e = 0; e < 4; ++e) {
            f[e]     = (short)f2bf((x[2 * kk][e]     - mean) * rsd);
            f[4 + e] = (short)f2bf((x[2 * kk + 1][e] - mean) * rsd);
        }
        Al[(wid * 6 + kk) * 64 + lane] = f;
    }
    __syncthreads();

    floatx4 acc[2][8];
    #pragma unroll
    for (int p = 0; p < 2; ++p)
        #pragma unroll
        for (int rg = 0; rg < 8; ++rg) acc[p][rg] = fzero4();

    if (wid < 4) {
        // ---- K tiles (swapped operands)
        #pragma unroll
        for (int rg = 0; rg < 8; ++rg)
            #pragma unroll
            for (int kk = 0; kk < 6; ++kk) {
                short8 a = Al[(rg * 6 + kk) * 64 + lane];
                acc[0][rg] = __builtin_amdgcn_mfma_f32_16x16x32_bf16(wf[0][kk], a, acc[0][rg], 0, 0, 0);
                acc[1][rg] = __builtin_amdgcn_mfma_f32_16x16x32_bf16(wf[1][kk], a, acc[1][rg], 0, 0, 0);
            }
        #pragma unroll
        for (int p = 0; p < 2; ++p) {
            int nt = nt0 + p;
            floatx4 bia = *(const floatx4*)(bias_kv + nt * 16 + g * 4);
            #pragma unroll
            for (int rg = 0; rg < 8; ++rg) {
                floatx4 vv;
                #pragma unroll
                for (int r = 0; r < 4; ++r) vv[r] = acc[p][rg][r] + bia[r];
                store_bf4(k1o + (size_t)(rowbase + rg * 16 + c) * 128 + nt * 16 + g * 4, vv);
            }
        }
    } else {
        // ---- V tiles (normal operands)
        #pragma unroll
        for (int rg = 0; rg < 8; ++rg)
            #pragma unroll
            for (int kk = 0; kk < 6; ++kk) {
                short8 a = Al[(rg * 6 + kk) * 64 + lane];
                acc[0][rg] = __builtin_amdgcn_mfma_f32_16x16x32_bf16(a, wf[0][kk], acc[0][rg], 0, 0, 0);
                acc[1][rg] = __builtin_amdgcn_mfma_f32_16x16x32_bf16(a, wf[1][kk], acc[1][rg], 0, 0, 0);
            }
        #pragma unroll
        for (int p = 0; p < 2; ++p) {
            int d = (nt0 + p - 8) * 16 + c;
            float bia = bias_kv[128 + d];
            size_t base = (((size_t)bb * 128 + d) << 12) + nbase;
            #pragma unroll
            for (int rg = 0; rg < 8; ++rg) {
                floatx4 vv;
                #pragma unroll
                for (int r = 0; r < 4; ++r) vv[r] = acc[p][rg][r] + bia;
                store_bf4(v1T + base + rg * 16 + g * 4, vv);
            }
        }
    }
}

// ---------------------------------------------------------------- K2: slot init + q for iter 0
__global__ __launch_bounds__(256)
void k2_init(const float* __restrict__ islots, const int* __restrict__ ip,
             const float* __restrict__ ln_s_g, const float* __restrict__ ln_s_b,
             const float* __restrict__ in_w, const float* __restrict__ in_b,
             const float* __restrict__ out_w, const float* __restrict__ out_b,
             const float* __restrict__ w1, const float* __restrict__ b1,
             const float* __restrict__ w2, const float* __restrict__ b2,
             const float* __restrict__ Wq_s, const float* __restrict__ bias_q,
             float* __restrict__ slotsA, float* __restrict__ qbuf) {
    __shared__ float sl[11][128];
    __shared__ float qkv[11][384];
    __shared__ float att[4][11][12];
    __shared__ float oh[11][128];
    __shared__ float s2l[11][128];
    __shared__ float s3[11][128];
    __shared__ float h1[11][256];
    float* fin = &oh[0][0];     // final slots (alias; oh dead by then)
    float* snq = &qkv[0][0];    // LN'd fin for q (alias; qkv dead by then)
    int t = threadIdx.x, lane = t & 63, wid = t >> 6;
    int bb = blockIdx.x;

    for (int s = wid; s < 11; s += 4) {
        const float* row = islots + ((size_t)bb * 11 + s) * 128;
        float x0 = row[lane], x1 = row[lane + 64];
        float s1 = x0 + x1, sq = x0 * x0 + x1 * x1;
        #pragma unroll
        for (int off = 32; off > 0; off >>= 1) { s1 += __shfl_xor(s1, off); sq += __shfl_xor(sq, off); }
        float mean = s1 * (1.f / 128.f), var = sq * (1.f / 128.f) - mean * mean;
        float rs = rsqrtf(var + 1e-5f);
        sl[s][lane]      = (x0 - mean) * rs * ln_s_g[lane]      + ln_s_b[lane];
        sl[s][lane + 64] = (x1 - mean) * rs * ln_s_g[lane + 64] + ln_s_b[lane + 64];
    }
    __syncthreads();
    int ival = *ip;
    if (ival != 1) {
        for (int o = t; o < 11 * 384; o += 256) {
            int s = o / 384, e = o % 384;
            const floatx4* w = (const floatx4*)(in_w + (size_t)e * 128);
            const floatx4* x = (const floatx4*)sl[s];
            float a = 0.f;
            for (int j = 0; j < 32; ++j) {
                floatx4 wv = w[j], xv = x[j];
                a += wv[0]*xv[0] + wv[1]*xv[1] + wv[2]*xv[2] + wv[3]*xv[3];
            }
            qkv[s][e] = a + in_b[e];
        }
        __syncthreads();
        for (int o = t; o < 4 * 11 * 11; o += 256) {
            int h = o / 121, ij = o % 121, i = ij / 11, j = ij % 11;
            const float* qr = &qkv[i][h * 32];
            const float* kr = &qkv[j][128 + h * 32];
            float a = 0.f;
            #pragma unroll
            for (int d = 0; d < 32; ++d) a += qr[d] * kr[d];
            att[h][i][j] = a * 0.17677669529663687f;
        }
        __syncthreads();
        if (t < 44) {
            int h = t / 11, i = t % 11;
            float mx = -1e30f;
            #pragma unroll
            for (int j = 0; j < 11; ++j) mx = fmaxf(mx, att[h][i][j]);
            float sum = 0.f, e_[11];
            #pragma unroll
            for (int j = 0; j < 11; ++j) { e_[j] = __expf(att[h][i][j] - mx); sum += e_[j]; }
            float inv = 1.f / sum;
            #pragma unroll
            for (int j = 0; j < 11; ++j) att[h][i][j] = e_[j] * inv;
        }
        __syncthreads();
        // oh into s2l path: compute oh into registers via temp buffer s3 (to keep fin alias safe)
        for (int o = t; o < 11 * 128; o += 256) {
            int s = o >> 7, e = o & 127, h = e >> 5;
            float a = 0.f;
            #pragma unroll
            for (int j = 0; j < 11; ++j) a += att[h][s][j] * qkv[j][256 + e];
            s3[s][e] = a;   // use s3 as oh scratch
        }
        __syncthreads();
        for (int o = t; o < 11 * 128; o += 256) {
            int s = o >> 7, e = o & 127;
            const floatx4* w = (const floatx4*)(out_w + (size_t)e * 128);
            const floatx4* x = (const floatx4*)s3[s];
            float a = 0.f;
            for (int j = 0; j < 32; ++j) {
                floatx4 wv = w[j], xv = x[j];
                a += wv[0]*xv[0] + wv[1]*xv[1] + wv[2]*xv[2] + wv[3]*xv[3];
            }
            s2l[s][e] = sl[s][e] + a + out_b[e];
        }
        __syncthreads();
        for (int s = wid; s < 11; s += 4) {
            float x0 = s2l[s][lane], x1 = s2l[s][lane + 64];
            float s1 = x0 + x1, sq = x0 * x0 + x1 * x1;
            #pragma unroll
            for (int off = 32; off > 0; off >>= 1) { s1 += __shfl_xor(s1, off); sq += __shfl_xor(sq, off); }
            float mean = s1 * (1.f / 128.f), var = sq * (1.f / 128.f) - mean * mean;
            float rs = rsqrtf(var + 1e-5f);
            s3[s][lane]      = (x0 - mean) * rs * ln_s_g[lane]      + ln_s_b[lane];
            s3[s][lane + 64] = (x1 - mean) * rs * ln_s_g[lane + 64] + ln_s_b[lane + 64];
        }
        __syncthreads();
        for (int o = t; o < 11 * 256; o += 256) {
            int s = o >> 8, k = o & 255;
            const floatx4* w = (const floatx4*)(w1 + (size_t)k * 128);
            const floatx4* x = (const floatx4*)s3[s];
            float a = 0.f;
            for (int j = 0; j < 32; ++j) {
                floatx4 wv = w[j], xv = x[j];
                a += wv[0]*xv[0] + wv[1]*xv[1] + wv[2]*xv[2] + wv[3]*xv[3];
            }
            a += b1[k];
            h1[s][k] = a > 0.f ? a : 0.f;
        }
        __syncthreads();
        for (int o = t; o < 11 * 128; o += 256) {
            int s = o >> 7, e = o & 127;
            const floatx4* w = (const floatx4*)(w2 + (size_t)e * 256);
            const floatx4* x = (const floatx4*)h1[s];
            float a = 0.f;
            for (int j = 0; j < 64; ++j) {
                floatx4 wv = w[j], xv = x[j];
                a += wv[0]*xv[0] + wv[1]*xv[1] + wv[2]*xv[2] + wv[3]*xv[3];
            }
            float val = s3[s][e] + a + b2[e];
            slotsA[((size_t)bb * 11 + s) * 128 + e] = val;
            fin[o] = val;
        }
    } else {
        for (int o = t; o < 11 * 128; o += 256) {
            int s = o >> 7, e = o & 127;
            float val = sl[s][e];
            slotsA[((size_t)bb * 11 + s) * 128 + e] = val;
            fin[o] = val;
        }
    }
    // ---- q epilogue (iter 0)
    __syncthreads();
    for (int s = wid; s < 11; s += 4) {
        float x0 = fin[s * 128 + lane], x1 = fin[s * 128 + lane + 64];
        float s1 = x0 + x1, sq = x0 * x0 + x1 * x1;
        #pragma unroll
        for (int off = 32; off > 0; off >>= 1) { s1 += __shfl_xor(s1, off); sq += __shfl_xor(sq, off); }
        float mean = s1 * (1.f / 128.f), var = sq * (1.f / 128.f) - mean * mean;
        float rs = rsqrtf(var + 1e-5f);
        snq[s * 128 + lane]      = (x0 - mean) * rs;
        snq[s * 128 + lane + 64] = (x1 - mean) * rs;
    }
    __syncthreads();
    for (int o = t; o < 11 * 128; o += 256) {
        int s = o >> 7, e = o & 127;
        const floatx4* w = (const floatx4*)(Wq_s + (size_t)e * 128);
        const floatx4* sp = (const floatx4*)(snq + s * 128);
        float a = 0.f;
        for (int j = 0; j < 32; ++j) {
            floatx4 wv = w[j], sv = sp[j];
            a += wv[0]*sv[0] + wv[1]*sv[1] + wv[2]*sv[2] + wv[3]*sv[3];
        }
        qbuf[((size_t)bb * 11 + s) * 128 + e] = a + bias_q[e];
    }
}

// ---------------------------------------------------------------- K4: slot attention main
#define LGP 17
#define PPAD 72
struct K4Arena {
    union {
        float Lg[64][LGP];
        float Ul[16][132];
    };
    unsigned short Pl[16][PPAD];
};
__global__ __launch_bounds__(256)
void k4_attn(const unsigned short* __restrict__ k1, const unsigned short* __restrict__ v1T,
             const float* __restrict__ qbuf, float* __restrict__ Upart, float* __restrict__ Spart) {
    __shared__ K4Arena ar[4];
    int t = threadIdx.x, lane = t & 63, wid = t >> 6;
    int bb = blockIdx.x >> 4;
    int part = blockIdx.x & 15;
    int n0 = part * 256 + wid * 64;
    int c = lane & 15, g = lane >> 4;
    K4Arena& A = ar[wid];

    short8 bq[4];
    #pragma unroll
    for (int kk = 0; kk < 4; ++kk) {
        short8 f;
        if (c < 11) {
            const floatx4* qp = (const floatx4*)(qbuf + ((size_t)bb * 11 + c) * 128 + kk * 32 + g * 8);
            floatx4 q0 = qp[0], q1 = qp[1];
            #pragma unroll
            for (int e = 0; e < 4; ++e) { f[e] = (short)f2bf(q0[e]); f[4 + e] = (short)f2bf(q1[e]); }
        } else {
            #pragma unroll
            for (int e = 0; e < 8; ++e) f[e] = 0;
        }
        bq[kk] = f;
    }

    floatx4 lac[4];
    #pragma unroll
    for (int t4 = 0; t4 < 4; ++t4) {
        lac[t4] = fzero4();
        #pragma unroll
        for (int kk = 0; kk < 4; ++kk) {
            const short8* ap = (const short8*)(k1 + ((size_t)bb * 4096 + n0 + t4 * 16 + c) * 128 + kk * 32 + g * 8);
            lac[t4] = __builtin_amdgcn_mfma_f32_16x16x32_bf16(*ap, bq[kk], lac[t4], 0, 0, 0);
        }
    }
    #pragma unroll
    for (int t4 = 0; t4 < 4; ++t4)
        #pragma unroll
        for (int r = 0; r < 4; ++r)
            A.Lg[t4 * 16 + g * 4 + r][c] = lac[t4][r];

    float p[11];
    {
        float mx = -1e30f;
        #pragma unroll
        for (int s = 0; s < 11; ++s) { p[s] = A.Lg[lane][s]; mx = fmaxf(mx, p[s]); }
        float sum = 0.f;
        #pragma unroll
        for (int s = 0; s < 11; ++s) { p[s] = __expf(p[s] - mx); sum += p[s]; }
        float inv = 1.f / sum;
        #pragma unroll
        for (int s = 0; s < 11; ++s) p[s] = p[s] * inv + 1e-8f;
    }
    #pragma unroll
    for (int s = 0; s < 11; ++s) A.Pl[s][lane] = f2bf(p[s]);

    floatx4 uac[8];
    floatx4 sac = fzero4();
    #pragma unroll
    for (int dt = 0; dt < 8; ++dt) uac[dt] = fzero4();
    short8 ones;
    #pragma unroll
    for (int e = 0; e < 8; ++e) ones[e] = (short)0x3F80;
    #pragma unroll
    for (int kk = 0; kk < 2; ++kk) {
        short8 ap = *(const short8*)(&A.Pl[c][kk * 32 + g * 8]);
        #pragma unroll
        for (int dt = 0; dt < 8; ++dt) {
            const short8* vp = (const short8*)(v1T + ((size_t)bb * 128 + dt * 16 + c) * 4096 + n0 + kk * 32 + g * 8);
            uac[dt] = __builtin_amdgcn_mfma_f32_16x16x32_bf16(ap, *vp, uac[dt], 0, 0, 0);
        }
        sac = __builtin_amdgcn_mfma_f32_16x16x32_bf16(ap, ones, sac, 0, 0, 0);
    }
    #pragma unroll
    for (int dt = 0; dt < 8; ++dt)
        #pragma unroll
        for (int r = 0; r < 4; ++r)
            A.Ul[g * 4 + r][dt * 16 + c] = uac[dt][r];
    if (c == 0) {
        #pragma unroll
        for (int r = 0; r < 4; ++r) A.Ul[g * 4 + r][128] = sac[r];
    }
    __syncthreads();
    for (int idx = t; idx < 11 * 129; idx += 256) {
        int s = idx / 129, cc = idx % 129;
        float v = ar[0].Ul[s][cc] + ar[1].Ul[s][cc] + ar[2].Ul[s][cc] + ar[3].Ul[s][cc];
        if (cc < 128) Upart[(((size_t)bb * 16 + part) * 11 + s) * 128 + cc] = v;
        else          Spart[((size_t)bb * 16 + part) * 11 + s] = v;
    }
}

// ---------------------------------------------------------------- K5: per-batch GRU + LN + MLP (+ q for next iter)
__global__ __launch_bounds__(256)
void k5_gru(const float* __restrict__ Upart, const float* __restrict__ Spart,
            const float* __restrict__ slots_prev,
            const float* __restrict__ wih, const float* __restrict__ whh,
            const float* __restrict__ bih, const float* __restrict__ bhh,
            const float* __restrict__ ln_m_g, const float* __restrict__ ln_m_b,
            const float* __restrict__ w1, const float* __restrict__ b1,
            const float* __restrict__ w2, const float* __restrict__ b2,
            const float* __restrict__ Wq_s, const float* __restrict__ bias_q,
            float* __restrict__ out, float* __restrict__ qbuf, int compute_q) {
    __shared__ float upd[11][128];
    __shared__ float sp[11][128];
    __shared__ float ssum[11];
    __shared__ float giL[11][384];
    __shared__ float ghL[11][384];
    __shared__ float nsb[11][128];
    __shared__ float mrow[11][128];
    __shared__ float hrow[11][256];
    float* fin = &mrow[0][0];   // reuse after mlp1 consumed mrow
    float* snq = &giL[0][0];    // reuse after gates consumed
    int t = threadIdx.x, lane = t & 63, wid = t >> 6;
    int bb = blockIdx.x;

    for (int o = t; o < 11 * 128; o += 256) {
        int s = o >> 7, e = o & 127;
        float ua = 0.f;
        #pragma unroll
        for (int pI = 0; pI < 16; ++pI)
            ua += Upart[(((size_t)bb * 16 + pI) * 11 + s) * 128 + e];
        upd[s][e] = ua;
        sp[s][e] = slots_prev[((size_t)bb * 11 + s) * 128 + e];
    }
    if (t < 11) {
        float sa = 0.f;
        #pragma unroll
        for (int pI = 0; pI < 16; ++pI) sa += Spart[((size_t)bb * 16 + pI) * 11 + t];
        ssum[t] = 1.f / sa;
    }
    __syncthreads();
    // gates: gi = (wih . upd)/ssum + bih ; gh = whh . sp + bhh
    for (int o = t; o < 11 * 384; o += 256) {
        int s = o / 384, e = o % 384;
        const floatx4* wi = (const floatx4*)(wih + (size_t)e * 128);
        const floatx4* wh = (const floatx4*)(whh + (size_t)e * 128);
        const floatx4* up = (const floatx4*)upd[s];
        const floatx4* spp = (const floatx4*)sp[s];
        float a1 = 0.f, a2 = 0.f;
        for (int j = 0; j < 32; ++j) {
            floatx4 wv = wi[j], uv = up[j];
            a1 += wv[0]*uv[0] + wv[1]*uv[1] + wv[2]*uv[2] + wv[3]*uv[3];
            floatx4 w2v = wh[j], sv = spp[j];
            a2 += w2v[0]*sv[0] + w2v[1]*sv[1] + w2v[2]*sv[2] + w2v[3]*sv[3];
        }
        giL[s][e] = a1 * ssum[s] + bih[e];
        ghL[s][e] = a2 + bhh[e];
    }
    __syncthreads();
    for (int o = t; o < 11 * 128; o += 256) {
        int s = o >> 7, e = o & 127;
        float r = 1.f / (1.f + __expf(-(giL[s][e] + ghL[s][e])));
        float z = 1.f / (1.f + __expf(-(giL[s][128 + e] + ghL[s][128 + e])));
        float nn = tanhf(giL[s][256 + e] + r * ghL[s][256 + e]);
        nsb[s][e] = (1.f - z) * nn + z * sp[s][e];
    }
    __syncthreads();
    for (int s = wid; s < 11; s += 4) {
        float x0 = nsb[s][lane], x1 = nsb[s][lane + 64];
        float s1 = x0 + x1, sq = x0 * x0 + x1 * x1;
        #pragma unroll
        for (int off = 32; off > 0; off >>= 1) { s1 += __shfl_xor(s1, off); sq += __shfl_xor(sq, off); }
        float mean = s1 * (1.f / 128.f), var = sq * (1.f / 128.f) - mean * mean;
        float rs = rsqrtf(var + 1e-5f);
        mrow[s][lane]      = (x0 - mean) * rs * ln_m_g[lane]      + ln_m_b[lane];
        mrow[s][lane + 64] = (x1 - mean) * rs * ln_m_g[lane + 64] + ln_m_b[lane + 64];
    }
    __syncthreads();
    for (int o = t; o < 11 * 256; o += 256) {
        int s = o >> 8, k = o & 255;
        const floatx4* wv = (const floatx4*)(w1 + (size_t)k * 128);
        const floatx4* mp = (const floatx4*)mrow[s];
        float a = 0.f;
        for (int j = 0; j < 32; ++j) {
            floatx4 w_ = wv[j], m_ = mp[j];
            a += w_[0]*m_[0] + w_[1]*m_[1] + w_[2]*m_[2] + w_[3]*m_[3];
        }
        a += b1[k];
        hrow[s][k] = a > 0.f ? a : 0.f;
    }
    __syncthreads();
    for (int o = t; o < 11 * 128; o += 256) {
        int s = o >> 7, e = o & 127;
        const floatx4* wv = (const floatx4*)(w2 + (size_t)e * 256);
        const floatx4* hp = (const floatx4*)hrow[s];
        float a = 0.f;
        for (int j = 0; j < 64; ++j) {
            floatx4 w_ = wv[j], h_ = hp[j];
            a += w_[0]*h_[0] + w_[1]*h_[1] + w_[2]*h_[2] + w_[3]*h_[3];
        }
        float val = nsb[s][e] + a + b2[e];
        out[((size_t)bb * 11 + s) * 128 + e] = val;
        fin[o] = val;
    }
    if (!compute_q) return;
    __syncthreads();
    for (int s = wid; s < 11; s += 4) {
        float x0 = fin[s * 128 + lane], x1 = fin[s * 128 + lane + 64];
        float s1 = x0 + x1, sq = x0 * x0 + x1 * x1;
        #pragma unroll
        for (int off = 32; off > 0; off >>= 1) { s1 += __shfl_xor(s1, off); sq += __shfl_xor(sq, off); }
        float mean = s1 * (1.f / 128.f), var = sq * (1.f / 128.f) - mean * mean;
        float rs = rsqrtf(var + 1e-5f);
        snq[s * 128 + lane]      = (x0 - mean) * rs;
        snq[s * 128 + lane + 64] = (x1 - mean) * rs;
    }
    __syncthreads();
    for (int o = t; o < 11 * 128; o += 256) {
        int s = o >> 7, e = o & 127;
        const floatx4* w = (const floatx4*)(Wq_s + (size_t)e * 128);
        const floatx4* sq = (const floatx4*)(snq + s * 128);
        float a = 0.f;
        for (int j = 0; j < 32; ++j) {
            floatx4 wv = w[j], sv = sq[j];
            a += wv[0]*sv[0] + wv[1]*sv[1] + wv[2]*sv[2] + wv[3]*sv[3];
        }
        qbuf[((size_t)bb * 11 + s) * 128 + e] = a + bias_q[e];
    }
}

// ---------------------------------------------------------------- host
extern "C" void kernel_launch(void* const* d_in, const int* in_sizes, int n_in,
                              void* d_out, int out_size, void* d_ws, size_t ws_size,
                              hipStream_t stream) {
    const float* inputs   = (const float*)d_in[0];
    const float* islots   = (const float*)d_in[1];
    const int*   ip       = (const int*)d_in[2];
    const float* ln_in_g  = (const float*)d_in[3];
    const float* ln_in_b  = (const float*)d_in[4];
    const float* ln_s_g   = (const float*)d_in[5];
    const float* ln_s_b   = (const float*)d_in[6];
    const float* ln_m_g   = (const float*)d_in[7];
    const float* ln_m_b   = (const float*)d_in[8];
    const float* mha_in_w = (const float*)d_in[9];
    const float* mha_in_b = (const float*)d_in[10];
    const float* mha_out_w= (const float*)d_in[11];
    const float* mha_out_b= (const float*)d_in[12];
    const float* attn_w1  = (const float*)d_in[13];
    const float* attn_b1  = (const float*)d_in[14];
    const float* attn_w2  = (const float*)d_in[15];
    const float* attn_b2  = (const float*)d_in[16];
    const float* Wq       = (const float*)d_in[17];
    const float* Wk       = (const float*)d_in[18];
    const float* Wv       = (const float*)d_in[19];
    const float* gru_wih  = (const float*)d_in[20];
    const float* gru_whh  = (const float*)d_in[21];
    const float* gru_bih  = (const float*)d_in[22];
    const float* gru_bhh  = (const float*)d_in[23];
    const float* mlp_w1   = (const float*)d_in[24];
    const float* mlp_b1   = (const float*)d_in[25];
    const float* mlp_w2   = (const float*)d_in[26];
    const float* mlp_b2   = (const float*)d_in[27];
    float* out = (float*)d_out;

    char* ws = (char*)d_ws;
    size_t off = 0;
    auto alloc = [&](size_t bytes) -> void* {
        void* p = ws + off;
        off += (bytes + 255) & ~(size_t)255;
        return p;
    };
    unsigned short* Wf    = (unsigned short*)alloc((size_t)256 * 192 * 2);
    float* bias_kv        = (float*)alloc(256 * 4);
    float* Wq_s           = (float*)alloc(128 * 128 * 4);
    float* bias_q         = (float*)alloc(128 * 4);
    unsigned short* k1    = (unsigned short*)alloc((size_t)64 * 4096 * 128 * 2);
    unsigned short* v1T   = (unsigned short*)alloc((size_t)64 * 128 * 4096 * 2);
    float* slotsA         = (float*)alloc((size_t)64 * 11 * 128 * 4);
    float* slotsB         = (float*)alloc((size_t)64 * 11 * 128 * 4);
    float* qbuf           = (float*)alloc((size_t)64 * 11 * 128 * 4);
    float* Upart          = (float*)alloc((size_t)64 * 16 * 11 * 128 * 4);
    float* Spart          = (float*)alloc((size_t)64 * 16 * 11 * 4);
    (void)ws_size; (void)in_sizes; (void)n_in; (void)out_size;

    k0_prep<<<384, 64, 0, stream>>>(Wk, Wv, ln_in_g, ln_in_b, Wq, ln_s_g, ln_s_b,
                                    Wf, bias_kv, Wq_s, bias_q);
    k1_lnproj<<<2048, 512, 0, stream>>>(inputs, Wf, bias_kv, k1, v1T);
    k2_init<<<64, 256, 0, stream>>>(islots, ip, ln_s_g, ln_s_b, mha_in_w, mha_in_b,
                                    mha_out_w, mha_out_b, attn_w1, attn_b1, attn_w2, attn_b2,
                                    Wq_s, bias_q, slotsA, qbuf);
    const float* sprev = slotsA;
    for (int it = 0; it < 2; ++it) {
        k4_attn<<<1024, 256, 0, stream>>>(k1, v1T, qbuf, Upart, Spart);
        float* dst = (it == 1) ? out : slotsB;
        k5_gru<<<64, 256, 0, stream>>>(Upart, Spart, sprev, gru_wih, gru_whh, gru_bih, gru_bhh,
                                       ln_m_g, ln_m_b, mlp_w1, mlp_b1, mlp_w2, mlp_b2,
                                       Wq_s, bias_q, dst, qbuf, (it == 0) ? 1 : 0);
        sprev = dst;
    }
}

// Round 4
// 445.549 us; speedup vs baseline: 1.4235x; 1.3822x over previous
//
#include <hip/hip_runtime.h>

typedef __attribute__((ext_vector_type(8))) short short8;
typedef __attribute__((ext_vector_type(4))) float floatx4;

#define B_  64
#define N_  4096
#define DIN 192
#define S_  11
#define E_  128

__device__ inline unsigned short f2bf(float f) {
    union { float f; unsigned u; } v; v.f = f;
    unsigned r = v.u + 0x7FFF + ((v.u >> 16) & 1);
    return (unsigned short)(r >> 16);
}
__device__ inline floatx4 fzero4() { floatx4 v; v[0]=v[1]=v[2]=v[3]=0.f; return v; }
__device__ inline void store_bf4(unsigned short* dst, floatx4 v) {
    union { unsigned short u[4]; unsigned long long q; } o;
    o.u[0] = f2bf(v[0]); o.u[1] = f2bf(v[1]); o.u[2] = f2bf(v[2]); o.u[3] = f2bf(v[3]);
    *(unsigned long long*)dst = o.q;
}

// ---------------------------------------------------------------- K0: weight prep
__global__ void k0_prep(const float* __restrict__ Wk, const float* __restrict__ Wv,
                        const float* __restrict__ ln_in_g, const float* __restrict__ ln_in_b,
                        const float* __restrict__ Wq, const float* __restrict__ ln_s_g,
                        const float* __restrict__ ln_s_b,
                        unsigned short* __restrict__ Wf, float* __restrict__ bias_kv,
                        float* __restrict__ Wq_s, float* __restrict__ bias_q) {
    int o = blockIdx.x, t = threadIdx.x;
    if (o < 256) {
        const float* src = (o < 128) ? (Wk + (size_t)o * DIN) : (Wv + (size_t)(o - 128) * DIN);
        int nt = o >> 4, cc = o & 15;
        float bs = 0.f;
        for (int j = t; j < DIN; j += 64) {
            float w = src[j];
            int kk = j >> 5, gg = (j >> 3) & 3, jj = j & 7;
            Wf[(size_t)(((nt * 6 + kk) << 6) + gg * 16 + cc) * 8 + jj] = f2bf(w * ln_in_g[j]);
            bs += w * ln_in_b[j];
        }
        #pragma unroll
        for (int off = 32; off > 0; off >>= 1) bs += __shfl_down(bs, off);
        if (t == 0) bias_kv[o] = bs;
    } else {
        int e = o - 256;
        const float sc = 0.08838834764831845f;  // 1/sqrt(128)
        float bs = 0.f;
        for (int j = t; j < E_; j += 64) {
            float w = Wq[(size_t)e * E_ + j];
            Wq_s[(size_t)e * E_ + j] = w * ln_s_g[j] * sc;
            bs += w * ln_s_b[j];
        }
        #pragma unroll
        for (int off = 32; off > 0; off >>= 1) bs += __shfl_down(bs, off);
        if (t == 0) bias_q[e] = bs * sc;
    }
}

// ---------------------------------------------------------------- K1: LN + K/V projection
__global__ __launch_bounds__(512, 2)
void k1_lnproj(const float* __restrict__ inp, const unsigned short* __restrict__ Wf,
               const float* __restrict__ bias_kv,
               unsigned short* __restrict__ k1o, unsigned short* __restrict__ v1T) {
    __shared__ short8 Al[8 * 6 * 64];   // 48 KB: [rg][kk][lane]
    int t = threadIdx.x, lane = t & 63, wid = t >> 6;
    long rowbase = (long)blockIdx.x * 128;
    int bb = (int)(rowbase >> 12);
    int nbase = (int)(rowbase & 4095);
    int c = lane & 15, g = lane >> 4;
    int nt0 = wid * 2;

    short8 wf[2][6];
    #pragma unroll
    for (int p = 0; p < 2; ++p)
        #pragma unroll
        for (int kk = 0; kk < 6; ++kk)
            wf[p][kk] = *(const short8*)(Wf + (size_t)(((nt0 + p) * 6 + kk) * 64 + lane) * 8);

    long row = rowbase + wid * 16 + c;
    const float* rp = inp + row * DIN;
    floatx4 x[12];
    #pragma unroll
    for (int kk = 0; kk < 6; ++kk) {
        x[2 * kk]     = *(const floatx4*)(rp + kk * 32 + g * 8);
        x[2 * kk + 1] = *(const floatx4*)(rp + kk * 32 + g * 8 + 4);
    }
    float s1 = 0.f, s2 = 0.f;
    #pragma unroll
    for (int j = 0; j < 12; ++j)
        #pragma unroll
        for (int e = 0; e < 4; ++e) { s1 += x[j][e]; s2 += x[j][e] * x[j][e]; }
    s1 += __shfl_xor(s1, 16); s1 += __shfl_xor(s1, 32);
    s2 += __shfl_xor(s2, 16); s2 += __shfl_xor(s2, 32);
    float mean = s1 * (1.f / 192.f);
    float var  = s2 * (1.f / 192.f) - mean * mean;
    float rsd  = rsqrtf(var + 1e-5f);
    #pragma unroll
    for (int kk = 0; kk < 6; ++kk) {
        short8 f;
        #pragma unroll
        for (int e = 0; e < 4; ++e) {
            f[e]     = (short)f2bf((x[2 * kk][e]     - mean) * rsd);
            f[4 + e] = (short)f2bf((x[2 * kk + 1][e] - mean) * rsd);
        }
        Al[(wid * 6 + kk) * 64 + lane] = f;
    }
    __syncthreads();

    floatx4 acc[2][8];
    #pragma unroll
    for (int p = 0; p < 2; ++p)
        #pragma unroll
        for (int rg = 0; rg < 8; ++rg) acc[p][rg] = fzero4();

    if (wid < 4) {
        #pragma unroll
        for (int rg = 0; rg < 8; ++rg)
            #pragma unroll
            for (int kk = 0; kk < 6; ++kk) {
                short8 a = Al[(rg * 6 + kk) * 64 + lane];
                acc[0][rg] = __builtin_amdgcn_mfma_f32_16x16x32_bf16(wf[0][kk], a, acc[0][rg], 0, 0, 0);
                acc[1][rg] = __builtin_amdgcn_mfma_f32_16x16x32_bf16(wf[1][kk], a, acc[1][rg], 0, 0, 0);
            }
        #pragma unroll
        for (int p = 0; p < 2; ++p) {
            int nt = nt0 + p;
            floatx4 bia = *(const floatx4*)(bias_kv + nt * 16 + g * 4);
            #pragma unroll
            for (int rg = 0; rg < 8; ++rg) {
                floatx4 vv;
                #pragma unroll
                for (int r = 0; r < 4; ++r) vv[r] = acc[p][rg][r] + bia[r];
                store_bf4(k1o + (size_t)(rowbase + rg * 16 + c) * 128 + nt * 16 + g * 4, vv);
            }
        }
    } else {
        #pragma unroll
        for (int rg = 0; rg < 8; ++rg)
            #pragma unroll
            for (int kk = 0; kk < 6; ++kk) {
                short8 a = Al[(rg * 6 + kk) * 64 + lane];
                acc[0][rg] = __builtin_amdgcn_mfma_f32_16x16x32_bf16(a, wf[0][kk], acc[0][rg], 0, 0, 0);
                acc[1][rg] = __builtin_amdgcn_mfma_f32_16x16x32_bf16(a, wf[1][kk], acc[1][rg], 0, 0, 0);
            }
        #pragma unroll
        for (int p = 0; p < 2; ++p) {
            int d = (nt0 + p - 8) * 16 + c;
            float bia = bias_kv[128 + d];
            size_t base = (((size_t)bb * 128 + d) << 12) + nbase;
            #pragma unroll
            for (int rg = 0; rg < 8; ++rg) {
                floatx4 vv;
                #pragma unroll
                for (int r = 0; r < 4; ++r) vv[r] = acc[p][rg][r] + bia;
                store_bf4(v1T + base + rg * 16 + g * 4, vv);
            }
        }
    }
}

// ---------------------------------------------------------------- K2: slot init + q for iter 0
__global__ __launch_bounds__(256)
void k2_init(const float* __restrict__ islots, const int* __restrict__ ip,
             const float* __restrict__ ln_s_g, const float* __restrict__ ln_s_b,
             const float* __restrict__ in_w, const float* __restrict__ in_b,
             const float* __restrict__ out_w, const float* __restrict__ out_b,
             const float* __restrict__ w1, const float* __restrict__ b1,
             const float* __restrict__ w2, const float* __restrict__ b2,
             const float* __restrict__ Wq_s, const float* __restrict__ bias_q,
             float* __restrict__ slotsA, float* __restrict__ qbuf) {
    __shared__ float sl[11][128];
    __shared__ float qkv[11][384];
    __shared__ float att[4][11][12];
    __shared__ float oh[11][128];
    __shared__ float s2l[11][128];
    __shared__ float s3[11][128];
    __shared__ float h1[11][256];
    float* fin = &oh[0][0];
    float* snq = &qkv[0][0];
    int t = threadIdx.x, lane = t & 63, wid = t >> 6;
    int bb = blockIdx.x;

    for (int s = wid; s < 11; s += 4) {
        const float* row = islots + ((size_t)bb * 11 + s) * 128;
        float x0 = row[lane], x1 = row[lane + 64];
        float s1 = x0 + x1, sq = x0 * x0 + x1 * x1;
        #pragma unroll
        for (int off = 32; off > 0; off >>= 1) { s1 += __shfl_xor(s1, off); sq += __shfl_xor(sq, off); }
        float mean = s1 * (1.f / 128.f), var = sq * (1.f / 128.f) - mean * mean;
        float rs = rsqrtf(var + 1e-5f);
        sl[s][lane]      = (x0 - mean) * rs * ln_s_g[lane]      + ln_s_b[lane];
        sl[s][lane + 64] = (x1 - mean) * rs * ln_s_g[lane + 64] + ln_s_b[lane + 64];
    }
    __syncthreads();
    int ival = *ip;
    if (ival != 1) {
        for (int o = t; o < 11 * 384; o += 256) {
            int s = o / 384, e = o % 384;
            const floatx4* w = (const floatx4*)(in_w + (size_t)e * 128);
            const floatx4* x = (const floatx4*)sl[s];
            float a = 0.f;
            for (int j = 0; j < 32; ++j) {
                floatx4 wv = w[j], xv = x[j];
                a += wv[0]*xv[0] + wv[1]*xv[1] + wv[2]*xv[2] + wv[3]*xv[3];
            }
            qkv[s][e] = a + in_b[e];
        }
        __syncthreads();
        for (int o = t; o < 4 * 11 * 11; o += 256) {
            int h = o / 121, ij = o % 121, i = ij / 11, j = ij % 11;
            const float* qr = &qkv[i][h * 32];
            const float* kr = &qkv[j][128 + h * 32];
            float a = 0.f;
            #pragma unroll
            for (int d = 0; d < 32; ++d) a += qr[d] * kr[d];
            att[h][i][j] = a * 0.17677669529663687f;
        }
        __syncthreads();
        if (t < 44) {
            int h = t / 11, i = t % 11;
            float mx = -1e30f;
            #pragma unroll
            for (int j = 0; j < 11; ++j) mx = fmaxf(mx, att[h][i][j]);
            float sum = 0.f, e_[11];
            #pragma unroll
            for (int j = 0; j < 11; ++j) { e_[j] = __expf(att[h][i][j] - mx); sum += e_[j]; }
            float inv = 1.f / sum;
            #pragma unroll
            for (int j = 0; j < 11; ++j) att[h][i][j] = e_[j] * inv;
        }
        __syncthreads();
        for (int o = t; o < 11 * 128; o += 256) {
            int s = o >> 7, e = o & 127, h = e >> 5;
            float a = 0.f;
            #pragma unroll
            for (int j = 0; j < 11; ++j) a += att[h][s][j] * qkv[j][256 + e];
            s3[s][e] = a;
        }
        __syncthreads();
        for (int o = t; o < 11 * 128; o += 256) {
            int s = o >> 7, e = o & 127;
            const floatx4* w = (const floatx4*)(out_w + (size_t)e * 128);
            const floatx4* x = (const floatx4*)s3[s];
            float a = 0.f;
            for (int j = 0; j < 32; ++j) {
                floatx4 wv = w[j], xv = x[j];
                a += wv[0]*xv[0] + wv[1]*xv[1] + wv[2]*xv[2] + wv[3]*xv[3];
            }
            s2l[s][e] = sl[s][e] + a + out_b[e];
        }
        __syncthreads();
        for (int s = wid; s < 11; s += 4) {
            float x0 = s2l[s][lane], x1 = s2l[s][lane + 64];
            float s1 = x0 + x1, sq = x0 * x0 + x1 * x1;
            #pragma unroll
            for (int off = 32; off > 0; off >>= 1) { s1 += __shfl_xor(s1, off); sq += __shfl_xor(sq, off); }
            float mean = s1 * (1.f / 128.f), var = sq * (1.f / 128.f) - mean * mean;
            float rs = rsqrtf(var + 1e-5f);
            s3[s][lane]      = (x0 - mean) * rs * ln_s_g[lane]      + ln_s_b[lane];
            s3[s][lane + 64] = (x1 - mean) * rs * ln_s_g[lane + 64] + ln_s_b[lane + 64];
        }
        __syncthreads();
        for (int o = t; o < 11 * 256; o += 256) {
            int s = o >> 8, k = o & 255;
            const floatx4* w = (const floatx4*)(w1 + (size_t)k * 128);
            const floatx4* x = (const floatx4*)s3[s];
            float a = 0.f;
            for (int j = 0; j < 32; ++j) {
                floatx4 wv = w[j], xv = x[j];
                a += wv[0]*xv[0] + wv[1]*xv[1] + wv[2]*xv[2] + wv[3]*xv[3];
            }
            a += b1[k];
            h1[s][k] = a > 0.f ? a : 0.f;
        }
        __syncthreads();
        for (int o = t; o < 11 * 128; o += 256) {
            int s = o >> 7, e = o & 127;
            const floatx4* w = (const floatx4*)(w2 + (size_t)e * 256);
            const floatx4* x = (const floatx4*)h1[s];
            float a = 0.f;
            for (int j = 0; j < 64; ++j) {
                floatx4 wv = w[j], xv = x[j];
                a += wv[0]*xv[0] + wv[1]*xv[1] + wv[2]*xv[2] + wv[3]*xv[3];
            }
            float val = s3[s][e] + a + b2[e];
            slotsA[((size_t)bb * 11 + s) * 128 + e] = val;
            fin[o] = val;
        }
    } else {
        for (int o = t; o < 11 * 128; o += 256) {
            int s = o >> 7, e = o & 127;
            float val = sl[s][e];
            slotsA[((size_t)bb * 11 + s) * 128 + e] = val;
            fin[o] = val;
        }
    }
    __syncthreads();
    for (int s = wid; s < 11; s += 4) {
        float x0 = fin[s * 128 + lane], x1 = fin[s * 128 + lane + 64];
        float s1 = x0 + x1, sq = x0 * x0 + x1 * x1;
        #pragma unroll
        for (int off = 32; off > 0; off >>= 1) { s1 += __shfl_xor(s1, off); sq += __shfl_xor(sq, off); }
        float mean = s1 * (1.f / 128.f), var = sq * (1.f / 128.f) - mean * mean;
        float rs = rsqrtf(var + 1e-5f);
        snq[s * 128 + lane]      = (x0 - mean) * rs;
        snq[s * 128 + lane + 64] = (x1 - mean) * rs;
    }
    __syncthreads();
    for (int o = t; o < 11 * 128; o += 256) {
        int s = o >> 7, e = o & 127;
        const floatx4* w = (const floatx4*)(Wq_s + (size_t)e * 128);
        const floatx4* sp = (const floatx4*)(snq + s * 128);
        float a = 0.f;
        for (int j = 0; j < 32; ++j) {
            floatx4 wv = w[j], sv = sp[j];
            a += wv[0]*sv[0] + wv[1]*sv[1] + wv[2]*sv[2] + wv[3]*sv[3];
        }
        qbuf[((size_t)bb * 11 + s) * 128 + e] = a + bias_q[e];
    }
}

// ---------------------------------------------------------------- K4: slot attention main
#define LGP 17
#define PPAD 72
struct K4Arena {
    union {
        float Lg[64][LGP];
        float Ul[16][132];
    };
    unsigned short Pl[16][PPAD];
};
__global__ __launch_bounds__(256)
void k4_attn(const unsigned short* __restrict__ k1, const unsigned short* __restrict__ v1T,
             const float* __restrict__ qbuf, float* __restrict__ Upart, float* __restrict__ Spart) {
    __shared__ K4Arena ar[4];
    int t = threadIdx.x, lane = t & 63, wid = t >> 6;
    int bb = blockIdx.x >> 4;
    int part = blockIdx.x & 15;
    int n0 = part * 256 + wid * 64;
    int c = lane & 15, g = lane >> 4;
    K4Arena& A = ar[wid];

    short8 bq[4];
    #pragma unroll
    for (int kk = 0; kk < 4; ++kk) {
        short8 f;
        if (c < 11) {
            const floatx4* qp = (const floatx4*)(qbuf + ((size_t)bb * 11 + c) * 128 + kk * 32 + g * 8);
            floatx4 q0 = qp[0], q1 = qp[1];
            #pragma unroll
            for (int e = 0; e < 4; ++e) { f[e] = (short)f2bf(q0[e]); f[4 + e] = (short)f2bf(q1[e]); }
        } else {
            #pragma unroll
            for (int e = 0; e < 8; ++e) f[e] = 0;
        }
        bq[kk] = f;
    }

    floatx4 lac[4];
    #pragma unroll
    for (int t4 = 0; t4 < 4; ++t4) {
        lac[t4] = fzero4();
        #pragma unroll
        for (int kk = 0; kk < 4; ++kk) {
            const short8* ap = (const short8*)(k1 + ((size_t)bb * 4096 + n0 + t4 * 16 + c) * 128 + kk * 32 + g * 8);
            lac[t4] = __builtin_amdgcn_mfma_f32_16x16x32_bf16(*ap, bq[kk], lac[t4], 0, 0, 0);
        }
    }
    #pragma unroll
    for (int t4 = 0; t4 < 4; ++t4)
        #pragma unroll
        for (int r = 0; r < 4; ++r)
            A.Lg[t4 * 16 + g * 4 + r][c] = lac[t4][r];

    float p[11];
    {
        float mx = -1e30f;
        #pragma unroll
        for (int s = 0; s < 11; ++s) { p[s] = A.Lg[lane][s]; mx = fmaxf(mx, p[s]); }
        float sum = 0.f;
        #pragma unroll
        for (int s = 0; s < 11; ++s) { p[s] = __expf(p[s] - mx); sum += p[s]; }
        float inv = 1.f / sum;
        #pragma unroll
        for (int s = 0; s < 11; ++s) p[s] = p[s] * inv + 1e-8f;
    }
    #pragma unroll
    for (int s = 0; s < 11; ++s) A.Pl[s][lane] = f2bf(p[s]);

    floatx4 uac[8];
    floatx4 sac = fzero4();
    #pragma unroll
    for (int dt = 0; dt < 8; ++dt) uac[dt] = fzero4();
    short8 ones;
    #pragma unroll
    for (int e = 0; e < 8; ++e) ones[e] = (short)0x3F80;
    #pragma unroll
    for (int kk = 0; kk < 2; ++kk) {
        short8 ap = *(const short8*)(&A.Pl[c][kk * 32 + g * 8]);
        #pragma unroll
        for (int dt = 0; dt < 8; ++dt) {
            const short8* vp = (const short8*)(v1T + ((size_t)bb * 128 + dt * 16 + c) * 4096 + n0 + kk * 32 + g * 8);
            uac[dt] = __builtin_amdgcn_mfma_f32_16x16x32_bf16(ap, *vp, uac[dt], 0, 0, 0);
        }
        sac = __builtin_amdgcn_mfma_f32_16x16x32_bf16(ap, ones, sac, 0, 0, 0);
    }
    #pragma unroll
    for (int dt = 0; dt < 8; ++dt)
        #pragma unroll
        for (int r = 0; r < 4; ++r)
            A.Ul[g * 4 + r][dt * 16 + c] = uac[dt][r];
    if (c == 0) {
        #pragma unroll
        for (int r = 0; r < 4; ++r) A.Ul[g * 4 + r][128] = sac[r];
    }
    __syncthreads();
    for (int idx = t; idx < 11 * 129; idx += 256) {
        int s = idx / 129, cc = idx % 129;
        float v = ar[0].Ul[s][cc] + ar[1].Ul[s][cc] + ar[2].Ul[s][cc] + ar[3].Ul[s][cc];
        if (cc < 128) Upart[(((size_t)bb * 16 + part) * 11 + s) * 128 + cc] = v;
        else          Spart[((size_t)bb * 16 + part) * 11 + s] = v;
    }
}

// ---------------------------------------------------------------- K5: per-(b,s) GRU + LN + MLP (+ q for next iter)
__global__ __launch_bounds__(128)
void k5_gru(const float* __restrict__ Upart, const float* __restrict__ Spart,
            const float* __restrict__ slots_prev,
            const float* __restrict__ wih, const float* __restrict__ whh,
            const float* __restrict__ bih, const float* __restrict__ bhh,
            const float* __restrict__ ln_m_g, const float* __restrict__ ln_m_b,
            const float* __restrict__ w1, const float* __restrict__ b1,
            const float* __restrict__ w2, const float* __restrict__ b2,
            const float* __restrict__ Wq_s, const float* __restrict__ bias_q,
            float* __restrict__ out, float* __restrict__ qbuf, int compute_q) {
    __shared__ float upd[128];
    __shared__ float sp[128];
    __shared__ float mrow[128];
    __shared__ float hrow[256];
    __shared__ float red[4];
    __shared__ float red2[4];
    __shared__ float snq[128];
    int t = threadIdx.x;
    int bb = blockIdx.x / 11, s = blockIdx.x % 11;
    float ua = 0.f, sa = 0.f;
    #pragma unroll
    for (int pI = 0; pI < 16; ++pI) {
        ua += Upart[(((size_t)bb * 16 + pI) * 11 + s) * 128 + t];
        sa += Spart[((size_t)bb * 16 + pI) * 11 + s];
    }
    upd[t] = ua / sa;
    float spv = slots_prev[((size_t)bb * 11 + s) * 128 + t];
    sp[t] = spv;
    __syncthreads();
    float gi[3], gh[3];
    #pragma unroll
    for (int kI = 0; kI < 3; ++kI) {
        int e = t + kI * 128;
        const floatx4* wi = (const floatx4*)(wih + (size_t)e * 128);
        const floatx4* wh = (const floatx4*)(whh + (size_t)e * 128);
        const floatx4* up = (const floatx4*)upd;
        const floatx4* spp = (const floatx4*)sp;
        float a1 = 0.f, a2 = 0.f;
        for (int j = 0; j < 32; ++j) {
            floatx4 wv = wi[j], uv = up[j];
            a1 += wv[0]*uv[0] + wv[1]*uv[1] + wv[2]*uv[2] + wv[3]*uv[3];
            floatx4 w2v = wh[j], sv = spp[j];
            a2 += w2v[0]*sv[0] + w2v[1]*sv[1] + w2v[2]*sv[2] + w2v[3]*sv[3];
        }
        gi[kI] = a1 + bih[e];
        gh[kI] = a2 + bhh[e];
    }
    float r = 1.f / (1.f + __expf(-(gi[0] + gh[0])));
    float z = 1.f / (1.f + __expf(-(gi[1] + gh[1])));
    float nn = tanhf(gi[2] + r * gh[2]);
    float ns = (1.f - z) * nn + z * spv;
    float s1 = ns, s2 = ns * ns;
    #pragma unroll
    for (int off = 32; off > 0; off >>= 1) { s1 += __shfl_xor(s1, off); s2 += __shfl_xor(s2, off); }
    if ((t & 63) == 0) { red[(t >> 6) * 2] = s1; red[(t >> 6) * 2 + 1] = s2; }
    __syncthreads();
    float tot1 = red[0] + red[2], tot2 = red[1] + red[3];
    float mean = tot1 * (1.f / 128.f), var = tot2 * (1.f / 128.f) - mean * mean;
    float rs = rsqrtf(var + 1e-5f);
    mrow[t] = (ns - mean) * rs * ln_m_g[t] + ln_m_b[t];
    __syncthreads();
    #pragma unroll
    for (int kI = 0; kI < 2; ++kI) {
        int k = t + kI * 128;
        const floatx4* wv = (const floatx4*)(w1 + (size_t)k * 128);
        const floatx4* mp = (const floatx4*)mrow;
        float a = 0.f;
        for (int j = 0; j < 32; ++j) {
            floatx4 w_ = wv[j], m_ = mp[j];
            a += w_[0]*m_[0] + w_[1]*m_[1] + w_[2]*m_[2] + w_[3]*m_[3];
        }
        a += b1[k];
        hrow[k] = a > 0.f ? a : 0.f;
    }
    __syncthreads();
    float val;
    {
        const floatx4* wv = (const floatx4*)(w2 + (size_t)t * 256);
        const floatx4* hp = (const floatx4*)hrow;
        float a = 0.f;
        for (int j = 0; j < 64; ++j) {
            floatx4 w_ = wv[j], h_ = hp[j];
            a += w_[0]*h_[0] + w_[1]*h_[1] + w_[2]*h_[2] + w_[3]*h_[3];
        }
        val = ns + a + b2[t];
        out[((size_t)bb * 11 + s) * 128 + t] = val;
    }
    if (!compute_q) return;
    // ---- q epilogue for next iteration
    float q1 = val, q2 = val * val;
    #pragma unroll
    for (int off = 32; off > 0; off >>= 1) { q1 += __shfl_xor(q1, off); q2 += __shfl_xor(q2, off); }
    if ((t & 63) == 0) { red2[(t >> 6) * 2] = q1; red2[(t >> 6) * 2 + 1] = q2; }
    __syncthreads();
    float qt1 = red2[0] + red2[2], qt2 = red2[1] + red2[3];
    float qmean = qt1 * (1.f / 128.f), qvar = qt2 * (1.f / 128.f) - qmean * qmean;
    float qrs = rsqrtf(qvar + 1e-5f);
    snq[t] = (val - qmean) * qrs;
    __syncthreads();
    {
        const floatx4* w = (const floatx4*)(Wq_s + (size_t)t * 128);
        const floatx4* sq = (const floatx4*)snq;
        float a = 0.f;
        for (int j = 0; j < 32; ++j) {
            floatx4 wv = w[j], sv = sq[j];
            a += wv[0]*sv[0] + wv[1]*sv[1] + wv[2]*sv[2] + wv[3]*sv[3];
        }
        qbuf[((size_t)bb * 11 + s) * 128 + t] = a + bias_q[t];
    }
}

// ---------------------------------------------------------------- host
extern "C" void kernel_launch(void* const* d_in, const int* in_sizes, int n_in,
                              void* d_out, int out_size, void* d_ws, size_t ws_size,
                              hipStream_t stream) {
    const float* inputs   = (const float*)d_in[0];
    const float* islots   = (const float*)d_in[1];
    const int*   ip       = (const int*)d_in[2];
    const float* ln_in_g  = (const float*)d_in[3];
    const float* ln_in_b  = (const float*)d_in[4];
    const float* ln_s_g   = (const float*)d_in[5];
    const float* ln_s_b   = (const float*)d_in[6];
    const float* ln_m_g   = (const float*)d_in[7];
    const float* ln_m_b   = (const float*)d_in[8];
    const float* mha_in_w = (const float*)d_in[9];
    const float* mha_in_b = (const float*)d_in[10];
    const float* mha_out_w= (const float*)d_in[11];
    const float* mha_out_b= (const float*)d_in[12];
    const float* attn_w1  = (const float*)d_in[13];
    const float* attn_b1  = (const float*)d_in[14];
    const float* attn_w2  = (const float*)d_in[15];
    const float* attn_b2  = (const float*)d_in[16];
    const float* Wq       = (const float*)d_in[17];
    const float* Wk       = (const float*)d_in[18];
    const float* Wv       = (const float*)d_in[19];
    const float* gru_wih  = (const float*)d_in[20];
    const float* gru_whh  = (const float*)d_in[21];
    const float* gru_bih  = (const float*)d_in[22];
    const float* gru_bhh  = (const float*)d_in[23];
    const float* mlp_w1   = (const float*)d_in[24];
    const float* mlp_b1   = (const float*)d_in[25];
    const float* mlp_w2   = (const float*)d_in[26];
    const float* mlp_b2   = (const float*)d_in[27];
    float* out = (float*)d_out;

    char* ws = (char*)d_ws;
    size_t off = 0;
    auto alloc = [&](size_t bytes) -> void* {
        void* p = ws + off;
        off += (bytes + 255) & ~(size_t)255;
        return p;
    };
    unsigned short* Wf    = (unsigned short*)alloc((size_t)256 * 192 * 2);
    float* bias_kv        = (float*)alloc(256 * 4);
    float* Wq_s           = (float*)alloc(128 * 128 * 4);
    float* bias_q         = (float*)alloc(128 * 4);
    unsigned short* k1    = (unsigned short*)alloc((size_t)64 * 4096 * 128 * 2);
    unsigned short* v1T   = (unsigned short*)alloc((size_t)64 * 128 * 4096 * 2);
    float* slotsA         = (float*)alloc((size_t)64 * 11 * 128 * 4);
    float* slotsB         = (float*)alloc((size_t)64 * 11 * 128 * 4);
    float* qbuf           = (float*)alloc((size_t)64 * 11 * 128 * 4);
    float* Upart          = (float*)alloc((size_t)64 * 16 * 11 * 128 * 4);
    float* Spart          = (float*)alloc((size_t)64 * 16 * 11 * 4);
    (void)ws_size; (void)in_sizes; (void)n_in; (void)out_size;

    k0_prep<<<384, 64, 0, stream>>>(Wk, Wv, ln_in_g, ln_in_b, Wq, ln_s_g, ln_s_b,
                                    Wf, bias_kv, Wq_s, bias_q);
    k1_lnproj<<<2048, 512, 0, stream>>>(inputs, Wf, bias_kv, k1, v1T);
    k2_init<<<64, 256, 0, stream>>>(islots, ip, ln_s_g, ln_s_b, mha_in_w, mha_in_b,
                                    mha_out_w, mha_out_b, attn_w1, attn_b1, attn_w2, attn_b2,
                                    Wq_s, bias_q, slotsA, qbuf);
    const float* sprev = slotsA;
    for (int it = 0; it < 2; ++it) {
        k4_attn<<<1024, 256, 0, stream>>>(k1, v1T, qbuf, Upart, Spart);
        float* dst = (it == 1) ? out : slotsB;
        k5_gru<<<704, 128, 0, stream>>>(Upart, Spart, sprev, gru_wih, gru_whh, gru_bih, gru_bhh,
                                        ln_m_g, ln_m_b, mlp_w1, mlp_b1, mlp_w2, mlp_b2,
                                        Wq_s, bias_q, dst, qbuf, (it == 0) ? 1 : 0);
        sprev = dst;
    }
}

// Round 5
// 402.097 us; speedup vs baseline: 1.5774x; 1.1081x over previous
//
#include <hip/hip_runtime.h>

typedef __attribute__((ext_vector_type(8))) short short8;
typedef __attribute__((ext_vector_type(4))) float floatx4;

#define B_  64
#define N_  4096
#define DIN 192
#define S_  11
#define E_  128

__device__ inline unsigned short f2bf(float f) {
    union { float f; unsigned u; } v; v.f = f;
    unsigned r = v.u + 0x7FFF + ((v.u >> 16) & 1);
    return (unsigned short)(r >> 16);
}
__device__ inline floatx4 fzero4() { floatx4 v; v[0]=v[1]=v[2]=v[3]=0.f; return v; }
__device__ inline void store_bf4(unsigned short* dst, floatx4 v) {
    union { unsigned short u[4]; unsigned long long q; } o;
    o.u[0] = f2bf(v[0]); o.u[1] = f2bf(v[1]); o.u[2] = f2bf(v[2]); o.u[3] = f2bf(v[3]);
    *(unsigned long long*)dst = o.q;
}
__device__ inline float dot128(const float* __restrict__ w, const float* __restrict__ x) {
    const floatx4* wv = (const floatx4*)w;
    const floatx4* xv = (const floatx4*)x;
    float a = 0.f;
    for (int j = 0; j < 32; ++j) {
        floatx4 w_ = wv[j], x_ = xv[j];
        a += w_[0]*x_[0] + w_[1]*x_[1] + w_[2]*x_[2] + w_[3]*x_[3];
    }
    return a;
}
__device__ inline float dot256(const float* __restrict__ w, const float* __restrict__ x) {
    const floatx4* wv = (const floatx4*)w;
    const floatx4* xv = (const floatx4*)x;
    float a = 0.f;
    for (int j = 0; j < 64; ++j) {
        floatx4 w_ = wv[j], x_ = xv[j];
        a += w_[0]*x_[0] + w_[1]*x_[1] + w_[2]*x_[2] + w_[3]*x_[3];
    }
    return a;
}

// ---------------------------------------------------------------- K0: weight prep
__global__ void k0_prep(const float* __restrict__ Wk, const float* __restrict__ Wv,
                        const float* __restrict__ ln_in_g, const float* __restrict__ ln_in_b,
                        const float* __restrict__ Wq, const float* __restrict__ ln_s_g,
                        const float* __restrict__ ln_s_b,
                        unsigned short* __restrict__ Wf, float* __restrict__ bias_kv,
                        float* __restrict__ Wq_s, float* __restrict__ bias_q) {
    int o = blockIdx.x, t = threadIdx.x;
    if (o < 256) {
        const float* src = (o < 128) ? (Wk + (size_t)o * DIN) : (Wv + (size_t)(o - 128) * DIN);
        int nt = o >> 4, cc = o & 15;
        float bs = 0.f;
        for (int j = t; j < DIN; j += 64) {
            float w = src[j];
            int kk = j >> 5, gg = (j >> 3) & 3, jj = j & 7;
            Wf[(size_t)(((nt * 6 + kk) << 6) + gg * 16 + cc) * 8 + jj] = f2bf(w * ln_in_g[j]);
            bs += w * ln_in_b[j];
        }
        #pragma unroll
        for (int off = 32; off > 0; off >>= 1) bs += __shfl_down(bs, off);
        if (t == 0) bias_kv[o] = bs;
    } else {
        int e = o - 256;
        const float sc = 0.08838834764831845f;  // 1/sqrt(128)
        float bs = 0.f;
        for (int j = t; j < E_; j += 64) {
            float w = Wq[(size_t)e * E_ + j];
            Wq_s[(size_t)e * E_ + j] = w * ln_s_g[j] * sc;
            bs += w * ln_s_b[j];
        }
        #pragma unroll
        for (int off = 32; off > 0; off >>= 1) bs += __shfl_down(bs, off);
        if (t == 0) bias_q[e] = bs * sc;
    }
}

// ---------------------------------------------------------------- K1: LN + K/V projection
__global__ __launch_bounds__(512, 2)
void k1_lnproj(const float* __restrict__ inp, const unsigned short* __restrict__ Wf,
               const float* __restrict__ bias_kv,
               unsigned short* __restrict__ k1o, unsigned short* __restrict__ v1T) {
    __shared__ short8 Al[8 * 6 * 64];   // 48 KB: [rg][kk][lane]
    int t = threadIdx.x, lane = t & 63, wid = t >> 6;
    long rowbase = (long)blockIdx.x * 128;
    int bb = (int)(rowbase >> 12);
    int nbase = (int)(rowbase & 4095);
    int c = lane & 15, g = lane >> 4;
    int nt0 = wid * 2;

    short8 wf[2][6];
    #pragma unroll
    for (int p = 0; p < 2; ++p)
        #pragma unroll
        for (int kk = 0; kk < 6; ++kk)
            wf[p][kk] = *(const short8*)(Wf + (size_t)(((nt0 + p) * 6 + kk) * 64 + lane) * 8);

    long row = rowbase + wid * 16 + c;
    const float* rp = inp + row * DIN;
    floatx4 x[12];
    #pragma unroll
    for (int kk = 0; kk < 6; ++kk) {
        x[2 * kk]     = *(const floatx4*)(rp + kk * 32 + g * 8);
        x[2 * kk + 1] = *(const floatx4*)(rp + kk * 32 + g * 8 + 4);
    }
    float s1 = 0.f, s2 = 0.f;
    #pragma unroll
    for (int j = 0; j < 12; ++j)
        #pragma unroll
        for (int e = 0; e < 4; ++e) { s1 += x[j][e]; s2 += x[j][e] * x[j][e]; }
    s1 += __shfl_xor(s1, 16); s1 += __shfl_xor(s1, 32);
    s2 += __shfl_xor(s2, 16); s2 += __shfl_xor(s2, 32);
    float mean = s1 * (1.f / 192.f);
    float var  = s2 * (1.f / 192.f) - mean * mean;
    float rsd  = rsqrtf(var + 1e-5f);
    #pragma unroll
    for (int kk = 0; kk < 6; ++kk) {
        short8 f;
        #pragma unroll
        for (int e = 0; e < 4; ++e) {
            f[e]     = (short)f2bf((x[2 * kk][e]     - mean) * rsd);
            f[4 + e] = (short)f2bf((x[2 * kk + 1][e] - mean) * rsd);
        }
        Al[(wid * 6 + kk) * 64 + lane] = f;
    }
    __syncthreads();

    floatx4 acc[2][8];
    #pragma unroll
    for (int p = 0; p < 2; ++p)
        #pragma unroll
        for (int rg = 0; rg < 8; ++rg) acc[p][rg] = fzero4();

    if (wid < 4) {
        #pragma unroll
        for (int rg = 0; rg < 8; ++rg)
            #pragma unroll
            for (int kk = 0; kk < 6; ++kk) {
                short8 a = Al[(rg * 6 + kk) * 64 + lane];
                acc[0][rg] = __builtin_amdgcn_mfma_f32_16x16x32_bf16(wf[0][kk], a, acc[0][rg], 0, 0, 0);
                acc[1][rg] = __builtin_amdgcn_mfma_f32_16x16x32_bf16(wf[1][kk], a, acc[1][rg], 0, 0, 0);
            }
        #pragma unroll
        for (int p = 0; p < 2; ++p) {
            int nt = nt0 + p;
            floatx4 bia = *(const floatx4*)(bias_kv + nt * 16 + g * 4);
            #pragma unroll
            for (int rg = 0; rg < 8; ++rg) {
                floatx4 vv;
                #pragma unroll
                for (int r = 0; r < 4; ++r) vv[r] = acc[p][rg][r] + bia[r];
                store_bf4(k1o + (size_t)(rowbase + rg * 16 + c) * 128 + nt * 16 + g * 4, vv);
            }
        }
    } else {
        #pragma unroll
        for (int rg = 0; rg < 8; ++rg)
            #pragma unroll
            for (int kk = 0; kk < 6; ++kk) {
                short8 a = Al[(rg * 6 + kk) * 64 + lane];
                acc[0][rg] = __builtin_amdgcn_mfma_f32_16x16x32_bf16(a, wf[0][kk], acc[0][rg], 0, 0, 0);
                acc[1][rg] = __builtin_amdgcn_mfma_f32_16x16x32_bf16(a, wf[1][kk], acc[1][rg], 0, 0, 0);
            }
        #pragma unroll
        for (int p = 0; p < 2; ++p) {
            int d = (nt0 + p - 8) * 16 + c;
            float bia = bias_kv[128 + d];
            size_t base = (((size_t)bb * 128 + d) << 12) + nbase;
            #pragma unroll
            for (int rg = 0; rg < 8; ++rg) {
                floatx4 vv;
                #pragma unroll
                for (int r = 0; r < 4; ++r) vv[r] = acc[p][rg][r] + bia;
                store_bf4(v1T + base + rg * 16 + g * 4, vv);
            }
        }
    }
}

// ---------------------------------------------------------------- K2a: LN(islots) + qkv projection (per b,s)
__global__ __launch_bounds__(128)
void k2a_slots(const float* __restrict__ islots, const int* __restrict__ ip,
               const float* __restrict__ ln_s_g, const float* __restrict__ ln_s_b,
               const float* __restrict__ in_w, const float* __restrict__ in_b,
               const float* __restrict__ Wq_s, const float* __restrict__ bias_q,
               float* __restrict__ slbuf, float* __restrict__ qkvbuf,
               float* __restrict__ slotsA, float* __restrict__ qbuf) {
    __shared__ float sl[128];
    __shared__ float sn[128];
    __shared__ float red[4];
    int t = threadIdx.x;
    size_t bs = blockIdx.x;
    float x = islots[bs * 128 + t];
    float s1 = x, s2 = x * x;
    #pragma unroll
    for (int off = 32; off > 0; off >>= 1) { s1 += __shfl_xor(s1, off); s2 += __shfl_xor(s2, off); }
    if ((t & 63) == 0) { red[(t >> 6) * 2] = s1; red[(t >> 6) * 2 + 1] = s2; }
    __syncthreads();
    float tot1 = red[0] + red[2], tot2 = red[1] + red[3];
    float mean = tot1 * (1.f / 128.f), var = tot2 * (1.f / 128.f) - mean * mean;
    float rs = rsqrtf(var + 1e-5f);
    float slv = (x - mean) * rs * ln_s_g[t] + ln_s_b[t];
    sl[t] = slv;
    slbuf[bs * 128 + t] = slv;
    __syncthreads();
    int ival = *ip;
    if (ival != 1) {
        #pragma unroll
        for (int kI = 0; kI < 3; ++kI) {
            int e = t + kI * 128;
            qkvbuf[bs * 384 + e] = dot128(in_w + (size_t)e * 128, sl) + in_b[e];
        }
    } else {
        // slots = sl; write final init slots and q projection
        slotsA[bs * 128 + t] = slv;
        float q1 = slv, q2 = slv * slv;
        #pragma unroll
        for (int off = 32; off > 0; off >>= 1) { q1 += __shfl_xor(q1, off); q2 += __shfl_xor(q2, off); }
        __syncthreads();
        if ((t & 63) == 0) { red[(t >> 6) * 2] = q1; red[(t >> 6) * 2 + 1] = q2; }
        __syncthreads();
        float qt1 = red[0] + red[2], qt2 = red[1] + red[3];
        float qmean = qt1 * (1.f / 128.f), qvar = qt2 * (1.f / 128.f) - qmean * qmean;
        float qrs = rsqrtf(qvar + 1e-5f);
        sn[t] = (slv - qmean) * qrs;
        __syncthreads();
        qbuf[bs * 128 + t] = dot128(Wq_s + (size_t)t * 128, sn) + bias_q[t];
    }
}

// ---------------------------------------------------------------- K2b: MHA + MLP + q (per b,s)
__global__ __launch_bounds__(128)
void k2b_mha(const int* __restrict__ ip, const float* __restrict__ qkvbuf,
             const float* __restrict__ slbuf,
             const float* __restrict__ out_w, const float* __restrict__ out_b,
             const float* __restrict__ w1, const float* __restrict__ b1,
             const float* __restrict__ w2, const float* __restrict__ b2,
             const float* __restrict__ ln_s_g, const float* __restrict__ ln_s_b,
             const float* __restrict__ Wq_s, const float* __restrict__ bias_q,
             float* __restrict__ slotsA, float* __restrict__ qbuf) {
    if (*ip == 1) return;
    __shared__ float qv[128];
    __shared__ float att[4][12];
    __shared__ float oh[128];
    __shared__ float s3[128];
    __shared__ float h1[256];
    __shared__ float sn[128];
    __shared__ float red[4];
    int t = threadIdx.x;
    int bb = blockIdx.x / 11, s = blockIdx.x % 11;
    size_t base = (size_t)bb * 11;
    qv[t] = qkvbuf[(base + s) * 384 + t];
    __syncthreads();
    if (t < 44) {
        int h = t / 11, j = t % 11;
        const float* kr = qkvbuf + (base + j) * 384 + 128 + h * 32;
        const float* qr = &qv[h * 32];
        float a = 0.f;
        #pragma unroll
        for (int d = 0; d < 32; ++d) a += qr[d] * kr[d];
        att[h][j] = a * 0.17677669529663687f;
    }
    __syncthreads();
    if (t < 4) {
        float mx = -1e30f;
        #pragma unroll
        for (int j = 0; j < 11; ++j) mx = fmaxf(mx, att[t][j]);
        float sum = 0.f, e_[11];
        #pragma unroll
        for (int j = 0; j < 11; ++j) { e_[j] = __expf(att[t][j] - mx); sum += e_[j]; }
        float inv = 1.f / sum;
        #pragma unroll
        for (int j = 0; j < 11; ++j) att[t][j] = e_[j] * inv;
    }
    __syncthreads();
    {
        int h = t >> 5;
        float a = 0.f;
        #pragma unroll
        for (int j = 0; j < 11; ++j) a += att[h][j] * qkvbuf[(base + j) * 384 + 256 + t];
        oh[t] = a;
    }
    __syncthreads();
    float slv = slbuf[(base + s) * 128 + t];
    float s2v = slv + dot128(out_w + (size_t)t * 128, oh) + out_b[t];
    // LN (ln_s)
    float s1 = s2v, s2 = s2v * s2v;
    #pragma unroll
    for (int off = 32; off > 0; off >>= 1) { s1 += __shfl_xor(s1, off); s2 += __shfl_xor(s2, off); }
    if ((t & 63) == 0) { red[(t >> 6) * 2] = s1; red[(t >> 6) * 2 + 1] = s2; }
    __syncthreads();
    float tot1 = red[0] + red[2], tot2 = red[1] + red[3];
    float mean = tot1 * (1.f / 128.f), var = tot2 * (1.f / 128.f) - mean * mean;
    float rs = rsqrtf(var + 1e-5f);
    float s3v = (s2v - mean) * rs * ln_s_g[t] + ln_s_b[t];
    s3[t] = s3v;
    __syncthreads();
    #pragma unroll
    for (int kI = 0; kI < 2; ++kI) {
        int k = t + kI * 128;
        float a = dot128(w1 + (size_t)k * 128, s3) + b1[k];
        h1[k] = a > 0.f ? a : 0.f;
    }
    __syncthreads();
    float fin = s3v + dot256(w2 + (size_t)t * 256, h1) + b2[t];
    slotsA[(base + s) * 128 + t] = fin;
    // ---- q epilogue
    float q1 = fin, q2 = fin * fin;
    #pragma unroll
    for (int off = 32; off > 0; off >>= 1) { q1 += __shfl_xor(q1, off); q2 += __shfl_xor(q2, off); }
    __syncthreads();
    if ((t & 63) == 0) { red[(t >> 6) * 2] = q1; red[(t >> 6) * 2 + 1] = q2; }
    __syncthreads();
    float qt1 = red[0] + red[2], qt2 = red[1] + red[3];
    float qmean = qt1 * (1.f / 128.f), qvar = qt2 * (1.f / 128.f) - qmean * qmean;
    float qrs = rsqrtf(qvar + 1e-5f);
    sn[t] = (fin - qmean) * qrs;
    __syncthreads();
    qbuf[(base + s) * 128 + t] = dot128(Wq_s + (size_t)t * 128, sn) + bias_q[t];
}

// ---------------------------------------------------------------- K4: slot attention main
#define LGP 17
#define PPAD 72
struct K4Arena {
    union {
        float Lg[64][LGP];
        float Ul[16][132];
    };
    unsigned short Pl[16][PPAD];
};
__global__ __launch_bounds__(256)
void k4_attn(const unsigned short* __restrict__ k1, const unsigned short* __restrict__ v1T,
             const float* __restrict__ qbuf, float* __restrict__ Upart, float* __restrict__ Spart) {
    __shared__ K4Arena ar[4];
    int t = threadIdx.x, lane = t & 63, wid = t >> 6;
    int bb = blockIdx.x >> 4;
    int part = blockIdx.x & 15;
    int n0 = part * 256 + wid * 64;
    int c = lane & 15, g = lane >> 4;
    K4Arena& A = ar[wid];

    short8 bq[4];
    #pragma unroll
    for (int kk = 0; kk < 4; ++kk) {
        short8 f;
        if (c < 11) {
            const floatx4* qp = (const floatx4*)(qbuf + ((size_t)bb * 11 + c) * 128 + kk * 32 + g * 8);
            floatx4 q0 = qp[0], q1 = qp[1];
            #pragma unroll
            for (int e = 0; e < 4; ++e) { f[e] = (short)f2bf(q0[e]); f[4 + e] = (short)f2bf(q1[e]); }
        } else {
            #pragma unroll
            for (int e = 0; e < 8; ++e) f[e] = 0;
        }
        bq[kk] = f;
    }

    floatx4 lac[4];
    #pragma unroll
    for (int t4 = 0; t4 < 4; ++t4) {
        lac[t4] = fzero4();
        #pragma unroll
        for (int kk = 0; kk < 4; ++kk) {
            const short8* ap = (const short8*)(k1 + ((size_t)bb * 4096 + n0 + t4 * 16 + c) * 128 + kk * 32 + g * 8);
            lac[t4] = __builtin_amdgcn_mfma_f32_16x16x32_bf16(*ap, bq[kk], lac[t4], 0, 0, 0);
        }
    }
    #pragma unroll
    for (int t4 = 0; t4 < 4; ++t4)
        #pragma unroll
        for (int r = 0; r < 4; ++r)
            A.Lg[t4 * 16 + g * 4 + r][c] = lac[t4][r];

    float p[11];
    {
        float mx = -1e30f;
        #pragma unroll
        for (int s = 0; s < 11; ++s) { p[s] = A.Lg[lane][s]; mx = fmaxf(mx, p[s]); }
        float sum = 0.f;
        #pragma unroll
        for (int s = 0; s < 11; ++s) { p[s] = __expf(p[s] - mx); sum += p[s]; }
        float inv = 1.f / sum;
        #pragma unroll
        for (int s = 0; s < 11; ++s) p[s] = p[s] * inv + 1e-8f;
    }
    #pragma unroll
    for (int s = 0; s < 11; ++s) A.Pl[s][lane] = f2bf(p[s]);

    floatx4 uac[8];
    floatx4 sac = fzero4();
    #pragma unroll
    for (int dt = 0; dt < 8; ++dt) uac[dt] = fzero4();
    short8 ones;
    #pragma unroll
    for (int e = 0; e < 8; ++e) ones[e] = (short)0x3F80;
    #pragma unroll
    for (int kk = 0; kk < 2; ++kk) {
        short8 ap = *(const short8*)(&A.Pl[c][kk * 32 + g * 8]);
        #pragma unroll
        for (int dt = 0; dt < 8; ++dt) {
            const short8* vp = (const short8*)(v1T + ((size_t)bb * 128 + dt * 16 + c) * 4096 + n0 + kk * 32 + g * 8);
            uac[dt] = __builtin_amdgcn_mfma_f32_16x16x32_bf16(ap, *vp, uac[dt], 0, 0, 0);
        }
        sac = __builtin_amdgcn_mfma_f32_16x16x32_bf16(ap, ones, sac, 0, 0, 0);
    }
    #pragma unroll
    for (int dt = 0; dt < 8; ++dt)
        #pragma unroll
        for (int r = 0; r < 4; ++r)
            A.Ul[g * 4 + r][dt * 16 + c] = uac[dt][r];
    if (c == 0) {
        #pragma unroll
        for (int r = 0; r < 4; ++r) A.Ul[g * 4 + r][128] = sac[r];
    }
    __syncthreads();
    for (int idx = t; idx < 11 * 129; idx += 256) {
        int s = idx / 129, cc = idx % 129;
        float v = ar[0].Ul[s][cc] + ar[1].Ul[s][cc] + ar[2].Ul[s][cc] + ar[3].Ul[s][cc];
        if (cc < 128) Upart[(((size_t)bb * 16 + part) * 11 + s) * 128 + cc] = v;
        else          Spart[((size_t)bb * 16 + part) * 11 + s] = v;
    }
}

// ---------------------------------------------------------------- K5: per-(b,s) GRU + LN + MLP (+ q for next iter)
__global__ __launch_bounds__(128)
void k5_gru(const float* __restrict__ Upart, const float* __restrict__ Spart,
            const float* __restrict__ slots_prev,
            const float* __restrict__ wih, const float* __restrict__ whh,
            const float* __restrict__ bih, const float* __restrict__ bhh,
            const float* __restrict__ ln_m_g, const float* __restrict__ ln_m_b,
            const float* __restrict__ w1, const float* __restrict__ b1,
            const float* __restrict__ w2, const float* __restrict__ b2,
            const float* __restrict__ Wq_s, const float* __restrict__ bias_q,
            float* __restrict__ out, float* __restrict__ qbuf, int compute_q) {
    __shared__ float upd[128];
    __shared__ float sp[128];
    __shared__ float mrow[128];
    __shared__ float hrow[256];
    __shared__ float red[4];
    __shared__ float red2[4];
    __shared__ float snq[128];
    int t = threadIdx.x;
    int bb = blockIdx.x / 11, s = blockIdx.x % 11;
    float ua = 0.f, sa = 0.f;
    #pragma unroll
    for (int pI = 0; pI < 16; ++pI) {
        ua += Upart[(((size_t)bb * 16 + pI) * 11 + s) * 128 + t];
        sa += Spart[((size_t)bb * 16 + pI) * 11 + s];
    }
    upd[t] = ua / sa;
    float spv = slots_prev[((size_t)bb * 11 + s) * 128 + t];
    sp[t] = spv;
    __syncthreads();
    float gi[3], gh[3];
    #pragma unroll
    for (int kI = 0; kI < 3; ++kI) {
        int e = t + kI * 128;
        const floatx4* wi = (const floatx4*)(wih + (size_t)e * 128);
        const floatx4* wh = (const floatx4*)(whh + (size_t)e * 128);
        const floatx4* up = (const floatx4*)upd;
        const floatx4* spp = (const floatx4*)sp;
        float a1 = 0.f, a2 = 0.f;
        for (int j = 0; j < 32; ++j) {
            floatx4 wv = wi[j], uv = up[j];
            a1 += wv[0]*uv[0] + wv[1]*uv[1] + wv[2]*uv[2] + wv[3]*uv[3];
            floatx4 w2v = wh[j], sv = spp[j];
            a2 += w2v[0]*sv[0] + w2v[1]*sv[1] + w2v[2]*sv[2] + w2v[3]*sv[3];
        }
        gi[kI] = a1 + bih[e];
        gh[kI] = a2 + bhh[e];
    }
    float r = 1.f / (1.f + __expf(-(gi[0] + gh[0])));
    float z = 1.f / (1.f + __expf(-(gi[1] + gh[1])));
    float nn = tanhf(gi[2] + r * gh[2]);
    float ns = (1.f - z) * nn + z * spv;
    float s1 = ns, s2 = ns * ns;
    #pragma unroll
    for (int off = 32; off > 0; off >>= 1) { s1 += __shfl_xor(s1, off); s2 += __shfl_xor(s2, off); }
    if ((t & 63) == 0) { red[(t >> 6) * 2] = s1; red[(t >> 6) * 2 + 1] = s2; }
    __syncthreads();
    float tot1 = red[0] + red[2], tot2 = red[1] + red[3];
    float mean = tot1 * (1.f / 128.f), var = tot2 * (1.f / 128.f) - mean * mean;
    float rs = rsqrtf(var + 1e-5f);
    mrow[t] = (ns - mean) * rs * ln_m_g[t] + ln_m_b[t];
    __syncthreads();
    #pragma unroll
    for (int kI = 0; kI < 2; ++kI) {
        int k = t + kI * 128;
        float a = dot128(w1 + (size_t)k * 128, mrow) + b1[k];
        hrow[k] = a > 0.f ? a : 0.f;
    }
    __syncthreads();
    float val;
    {
        val = ns + dot256(w2 + (size_t)t * 256, hrow) + b2[t];
        out[((size_t)bb * 11 + s) * 128 + t] = val;
    }
    if (!compute_q) return;
    float q1 = val, q2 = val * val;
    #pragma unroll
    for (int off = 32; off > 0; off >>= 1) { q1 += __shfl_xor(q1, off); q2 += __shfl_xor(q2, off); }
    if ((t & 63) == 0) { red2[(t >> 6) * 2] = q1; red2[(t >> 6) * 2 + 1] = q2; }
    __syncthreads();
    float qt1 = red2[0] + red2[2], qt2 = red2[1] + red2[3];
    float qmean = qt1 * (1.f / 128.f), qvar = qt2 * (1.f / 128.f) - qmean * qmean;
    float qrs = rsqrtf(qvar + 1e-5f);
    snq[t] = (val - qmean) * qrs;
    __syncthreads();
    qbuf[((size_t)bb * 11 + s) * 128 + t] = dot128(Wq_s + (size_t)t * 128, snq) + bias_q[t];
}

// ---------------------------------------------------------------- host
extern "C" void kernel_launch(void* const* d_in, const int* in_sizes, int n_in,
                              void* d_out, int out_size, void* d_ws, size_t ws_size,
                              hipStream_t stream) {
    const float* inputs   = (const float*)d_in[0];
    const float* islots   = (const float*)d_in[1];
    const int*   ip       = (const int*)d_in[2];
    const float* ln_in_g  = (const float*)d_in[3];
    const float* ln_in_b  = (const float*)d_in[4];
    const float* ln_s_g   = (const float*)d_in[5];
    const float* ln_s_b   = (const float*)d_in[6];
    const float* ln_m_g   = (const float*)d_in[7];
    const float* ln_m_b   = (const float*)d_in[8];
    const float* mha_in_w = (const float*)d_in[9];
    const float* mha_in_b = (const float*)d_in[10];
    const float* mha_out_w= (const float*)d_in[11];
    const float* mha_out_b= (const float*)d_in[12];
    const float* attn_w1  = (const float*)d_in[13];
    const float* attn_b1  = (const float*)d_in[14];
    const float* attn_w2  = (const float*)d_in[15];
    const float* attn_b2  = (const float*)d_in[16];
    const float* Wq       = (const float*)d_in[17];
    const float* Wk       = (const float*)d_in[18];
    const float* Wv       = (const float*)d_in[19];
    const float* gru_wih  = (const float*)d_in[20];
    const float* gru_whh  = (const float*)d_in[21];
    const float* gru_bih  = (const float*)d_in[22];
    const float* gru_bhh  = (const float*)d_in[23];
    const float* mlp_w1   = (const float*)d_in[24];
    const float* mlp_b1   = (const float*)d_in[25];
    const float* mlp_w2   = (const float*)d_in[26];
    const float* mlp_b2   = (const float*)d_in[27];
    float* out = (float*)d_out;

    char* ws = (char*)d_ws;
    size_t off = 0;
    auto alloc = [&](size_t bytes) -> void* {
        void* p = ws + off;
        off += (bytes + 255) & ~(size_t)255;
        return p;
    };
    unsigned short* Wf    = (unsigned short*)alloc((size_t)256 * 192 * 2);
    float* bias_kv        = (float*)alloc(256 * 4);
    float* Wq_s           = (float*)alloc(128 * 128 * 4);
    float* bias_q         = (float*)alloc(128 * 4);
    unsigned short* k1    = (unsigned short*)alloc((size_t)64 * 4096 * 128 * 2);
    unsigned short* v1T   = (unsigned short*)alloc((size_t)64 * 128 * 4096 * 2);
    float* slotsA         = (float*)alloc((size_t)64 * 11 * 128 * 4);
    float* slotsB         = (float*)alloc((size_t)64 * 11 * 128 * 4);
    float* qbuf           = (float*)alloc((size_t)64 * 11 * 128 * 4);
    float* Upart          = (float*)alloc((size_t)64 * 16 * 11 * 128 * 4);
    float* Spart          = (float*)alloc((size_t)64 * 16 * 11 * 4);
    float* slbuf          = (float*)alloc((size_t)64 * 11 * 128 * 4);
    float* qkvbuf         = (float*)alloc((size_t)64 * 11 * 384 * 4);
    (void)ws_size; (void)in_sizes; (void)n_in; (void)out_size;

    k0_prep<<<384, 64, 0, stream>>>(Wk, Wv, ln_in_g, ln_in_b, Wq, ln_s_g, ln_s_b,
                                    Wf, bias_kv, Wq_s, bias_q);
    k1_lnproj<<<2048, 512, 0, stream>>>(inputs, Wf, bias_kv, k1, v1T);
    k2a_slots<<<704, 128, 0, stream>>>(islots, ip, ln_s_g, ln_s_b, mha_in_w, mha_in_b,
                                       Wq_s, bias_q, slbuf, qkvbuf, slotsA, qbuf);
    k2b_mha<<<704, 128, 0, stream>>>(ip, qkvbuf, slbuf, mha_out_w, mha_out_b,
                                     attn_w1, attn_b1, attn_w2, attn_b2,
                                     ln_s_g, ln_s_b, Wq_s, bias_q, slotsA, qbuf);
    const float* sprev = slotsA;
    for (int it = 0; it < 2; ++it) {
        k4_attn<<<1024, 256, 0, stream>>>(k1, v1T, qbuf, Upart, Spart);
        float* dst = (it == 1) ? out : slotsB;
        k5_gru<<<704, 128, 0, stream>>>(Upart, Spart, sprev, gru_wih, gru_whh, gru_bih, gru_bhh,
                                        ln_m_g, ln_m_b, mlp_w1, mlp_b1, mlp_w2, mlp_b2,
                                        Wq_s, bias_q, dst, qbuf, (it == 0) ? 1 : 0);
        sprev = dst;
    }
}